// Round 7
// baseline (56.847 us; speedup 1.0000x reference)
//
#include <hip/hip_runtime.h>
#include <hip/hip_bf16.h>
#include <math.h>

typedef __attribute__((ext_vector_type(8))) short short8;
typedef __attribute__((ext_vector_type(4))) float f32x4;

__device__ __forceinline__ short f2bf(float f) {
    __hip_bfloat16 h = __float2bfloat16(f);   // RNE; compiler emits v_cvt_pk_bf16_f32 for pairs
    return __builtin_bit_cast(short, h);
}

// ============================================================================
// Kernel A0: one-time weight transpose + bf16 convert into d_ws.
// wT layout (shorts): W1T [128n][256k] @0 | W2T [64n][128k] @32768 |
//                     WcatT [192o][64k] @40960  (Wcat = [E1a|E1b|S1a|S1b])
// ============================================================================
__global__ __launch_bounds__(256)
void kernelA0(const float* __restrict__ W1, const float* __restrict__ W2,
              const float* __restrict__ E1, const float* __restrict__ S1,
              short* __restrict__ wT)
{
    const int tid = blockIdx.x * 256 + threadIdx.x;   // 64*256 = 16384
#pragma unroll
    for (int i = 0; i < 2; ++i) {                     // W1T: 32768 elems
        const int e = tid * 2 + i;
        const int n = e >> 8, k = e & 255;
        wT[e] = f2bf(W1[(size_t)k * 128 + n]);
    }
    if (tid < 8192) {                                 // W2T
        const int n = tid >> 7, k = tid & 127;
        wT[32768 + tid] = f2bf(W2[(size_t)k * 64 + n]);
    }
    if (tid < 12288) {                                // WcatT
        const int o = tid >> 6, k = tid & 63;
        float v;
        if (o < 64)       v = E1[(size_t)k * 64 + o];
        else if (o < 128) v = E1[(size_t)(64 + k) * 64 + (o - 64)];
        else if (o < 160) v = S1[(size_t)k * 32 + (o - 128)];
        else              v = S1[(size_t)(64 + k) * 32 + (o - 160)];
        wT[40960 + tid] = f2bf(v);
    }
}

// ============================================================================
// Fused kernel (round 7): node path (MFMA) + edge/strength stage, one block
// per batch. ei/ej/si/sj stay in LDS (was 16 MB ws round-trip + re-staging).
// MFMA lane mapping HW-validated rounds 4-6:
//   A[row=l&15][k=8*(l>>4)+e], B[k=8*(l>>4)+e][col=l&15], D[row=4*(l>>4)+q][col=l&15].
// ============================================================================
constexpr int H1B_S = 144;   // shorts
constexpr int NFB_S = 80;    // shorts
constexpr int EI2_S = 68;    // floats (eiR/ejR)
constexpr int SI2_S = 36;    // floats (siR/sjR)

__global__ __launch_bounds__(256, 1)
void kernelF(const float* __restrict__ x,
             const float* __restrict__ b1, const float* __restrict__ b2,
             const float* __restrict__ gamma, const float* __restrict__ beta,
             const short* __restrict__ wT,
             const float* __restrict__ bE1, const float* __restrict__ E2,
             const float* __restrict__ bE2, const float* __restrict__ E3,
             const float* __restrict__ bE3, const float* __restrict__ bS1,
             const float* __restrict__ S2, const float* __restrict__ bS2,
             float* __restrict__ out_nf, float* __restrict__ out_adj,
             float* __restrict__ out_str)
{
    __shared__ short h1B[64 * H1B_S];   // 18.4 KB (wave-private rows)
    __shared__ short nfB[64 * NFB_S];   // 10.2 KB
    __shared__ float eiR[64 * EI2_S];   // 17.4 KB, bE1 folded
    __shared__ float ejR[64 * EI2_S];   // 17.4 KB
    __shared__ float siR[64 * SI2_S];   //  9.2 KB, bS1 folded
    __shared__ float sjR[64 * SI2_S];   //  9.2 KB
    __shared__ float bE2s[32], E3s[32], S2s[32];
    // total ~80.4 KB -> 1 block/CU (grid=256 = 1/CU anyway)

    const int t = threadIdx.x, b = blockIdx.x;
    const int w = t >> 6, l = t & 63, g = l >> 4, r = l & 15;
    const short* W1T = wT;
    const short* W2T = wT + 32768;
    const short* WcT = wT + 40960;
    const int rowD = 16 * w + 4 * g;    // D-layout row base (+q)

    if (t < 32)       bE2s[t] = bE2[t];
    else if (t < 64)  E3s[t - 32] = E3[t - 32];
    else if (t < 96)  S2s[t - 64] = S2[t - 64];

    // ---- A-frags: gathered X rows -> bf16 registers ----
    const int mrow = 16 * w + r;
    const int srow = (mrow == 63) ? 127 : (int)((float)mrow * (127.0f / 63.0f));
    const float* xrow = x + ((size_t)b * 128 + srow) * 256;
    short8 aX[8];
#pragma unroll
    for (int ks = 0; ks < 8; ++ks) {
        const float4 v0 = *(const float4*)(xrow + 32 * ks + 8 * g);
        const float4 v1 = *(const float4*)(xrow + 32 * ks + 8 * g + 4);
        short8 a;
        a[0] = f2bf(v0.x); a[1] = f2bf(v0.y); a[2] = f2bf(v0.z); a[3] = f2bf(v0.w);
        a[4] = f2bf(v1.x); a[5] = f2bf(v1.y); a[6] = f2bf(v1.z); a[7] = f2bf(v1.w);
        aX[ks] = a;
    }

    // ---- phase 2: h1 = relu(X@W1 + b1); 2 acc chains for ILP ----
#pragma unroll
    for (int nt = 0; nt < 8; ++nt) {
        const int n = 16 * nt + r;
        f32x4 acca = {0.f, 0.f, 0.f, 0.f};
        f32x4 accb = {0.f, 0.f, 0.f, 0.f};
#pragma unroll
        for (int ks = 0; ks < 4; ++ks) {
            const short8 bwa = *(const short8*)(W1T + (size_t)n * 256 + 32 * ks + 8 * g);
            const short8 bwb = *(const short8*)(W1T + (size_t)n * 256 + 32 * (ks + 4) + 8 * g);
            acca = __builtin_amdgcn_mfma_f32_16x16x32_bf16(aX[ks], bwa, acca, 0, 0, 0);
            accb = __builtin_amdgcn_mfma_f32_16x16x32_bf16(aX[ks + 4], bwb, accb, 0, 0, 0);
        }
        const float b1v = b1[n];
#pragma unroll
        for (int q = 0; q < 4; ++q)
            h1B[(rowD + q) * H1B_S + n] = f2bf(fmaxf(acca[q] + accb[q] + b1v, 0.f));
    }

    // ---- phase 3: h = h1@W2 + b2 ----
    short8 ha[4];
#pragma unroll
    for (int ks = 0; ks < 4; ++ks)
        ha[ks] = *(const short8*)(&h1B[mrow * H1B_S + 32 * ks + 8 * g]);
    f32x4 hv[4];
#pragma unroll
    for (int nt = 0; nt < 4; ++nt) {
        const int n = 16 * nt + r;
        f32x4 acca = {0.f, 0.f, 0.f, 0.f};
        f32x4 accb = {0.f, 0.f, 0.f, 0.f};
#pragma unroll
        for (int ks = 0; ks < 2; ++ks) {
            const short8 bwa = *(const short8*)(W2T + (size_t)n * 128 + 32 * ks + 8 * g);
            const short8 bwb = *(const short8*)(W2T + (size_t)n * 128 + 32 * (ks + 2) + 8 * g);
            acca = __builtin_amdgcn_mfma_f32_16x16x32_bf16(ha[ks], bwa, acca, 0, 0, 0);
            accb = __builtin_amdgcn_mfma_f32_16x16x32_bf16(ha[ks + 2], bwb, accb, 0, 0, 0);
        }
        const float b2v = b2[n];
#pragma unroll
        for (int q = 0; q < 4; ++q) hv[nt][q] = acca[q] + accb[q] + b2v;
    }

    // ---- phase 4: LayerNorm in-register (16 lanes per row) ----
    float mu[4], rstd[4];
#pragma unroll
    for (int q = 0; q < 4; ++q) {
        float s = hv[0][q] + hv[1][q] + hv[2][q] + hv[3][q];
        s += __shfl_xor(s, 1); s += __shfl_xor(s, 2);
        s += __shfl_xor(s, 4); s += __shfl_xor(s, 8);
        mu[q] = s * (1.0f / 64.0f);
        float v = 0.f;
#pragma unroll
        for (int nt = 0; nt < 4; ++nt) { const float d = hv[nt][q] - mu[q]; v = fmaf(d, d, v); }
        v += __shfl_xor(v, 1); v += __shfl_xor(v, 2);
        v += __shfl_xor(v, 4); v += __shfl_xor(v, 8);
        rstd[q] = rsqrtf(v * (1.0f / 64.0f) + 1e-5f);
    }
#pragma unroll
    for (int nt = 0; nt < 4; ++nt) {
        const int n = 16 * nt + r;
        const float gv = gamma[n], bv = beta[n];
#pragma unroll
        for (int q = 0; q < 4; ++q) {
            const float nf = fmaf((hv[nt][q] - mu[q]) * rstd[q], gv, bv);
            out_nf[(size_t)b * 4096 + (size_t)(rowD + q) * 64 + n] = nf;
            nfB[(rowD + q) * NFB_S + n] = f2bf(nf);
        }
    }

    // ---- phase 5: [ei|ej|si|sj] = nf @ Wcat (K=64) -> LDS, biases folded ----
    const short8 na0 = *(const short8*)(&nfB[mrow * NFB_S + 8 * g]);
    const short8 na1 = *(const short8*)(&nfB[mrow * NFB_S + 32 + 8 * g]);
#pragma unroll
    for (int nt = 0; nt < 12; ++nt) {
        const int c = 16 * nt + r;
        const short8 bw0 = *(const short8*)(WcT + (size_t)c * 64 + 8 * g);
        const short8 bw1 = *(const short8*)(WcT + (size_t)c * 64 + 32 + 8 * g);
        f32x4 acc = {0.f, 0.f, 0.f, 0.f};
        acc = __builtin_amdgcn_mfma_f32_16x16x32_bf16(na0, bw0, acc, 0, 0, 0);
        acc = __builtin_amdgcn_mfma_f32_16x16x32_bf16(na1, bw1, acc, 0, 0, 0);
        if (nt < 4) {
            const float bv = bE1[c];
#pragma unroll
            for (int q = 0; q < 4; ++q) eiR[(rowD + q) * EI2_S + c] = acc[q] + bv;
        } else if (nt < 8) {
#pragma unroll
            for (int q = 0; q < 4; ++q) ejR[(rowD + q) * EI2_S + (c - 64)] = acc[q];
        } else if (nt < 10) {
            const float bv = bS1[c - 128];
#pragma unroll
            for (int q = 0; q < 4; ++q) siR[(rowD + q) * SI2_S + (c - 128)] = acc[q] + bv;
        } else {
#pragma unroll
            for (int q = 0; q < 4; ++q) sjR[(rowD + q) * SI2_S + (c - 160)] = acc[q];
        }
    }

    // ---- E2^T A-frag preload (global, all waves identical) ----
    short8 aE00, aE10, aE01, aE11;
#pragma unroll
    for (int e = 0; e < 8; ++e) {
        aE00[e] = f2bf(E2[(size_t)(8 * g + e) * 32 + r]);
        aE10[e] = f2bf(E2[(size_t)(8 * g + e + 32) * 32 + r]);
        aE01[e] = f2bf(E2[(size_t)(8 * g + e) * 32 + r + 16]);
        aE11[e] = f2bf(E2[(size_t)(8 * g + e + 32) * 32 + r + 16]);
    }
    const float bE3v = bE3[0], bS2v = bS2[0];
    __syncthreads();

    // ---- E pass: wave w owns i = 16w..16w+15; j-tiles 0..3 ----
    for (int jt = 0; jt < 4; ++jt) {
        const int j = (jt << 4) + r;
        const float4 ej00 = *(const float4*)&ejR[j * EI2_S + 8 * g];
        const float4 ej01 = *(const float4*)&ejR[j * EI2_S + 8 * g + 4];
        const float4 ej10 = *(const float4*)&ejR[j * EI2_S + 32 + 8 * g];
        const float4 ej11 = *(const float4*)&ejR[j * EI2_S + 32 + 8 * g + 4];

#pragma unroll
        for (int ii = 0; ii < 16; ++ii) {
            const int ig = 16 * w + ii;
            const float4 ei00 = *(const float4*)&eiR[ig * EI2_S + 8 * g];
            const float4 ei01 = *(const float4*)&eiR[ig * EI2_S + 8 * g + 4];
            const float4 ei10 = *(const float4*)&eiR[ig * EI2_S + 32 + 8 * g];
            const float4 ei11 = *(const float4*)&eiR[ig * EI2_S + 32 + 8 * g + 4];

            short8 b0, b1v;
            b0[0] = f2bf(fmaxf(ei00.x + ej00.x, 0.f));
            b0[1] = f2bf(fmaxf(ei00.y + ej00.y, 0.f));
            b0[2] = f2bf(fmaxf(ei00.z + ej00.z, 0.f));
            b0[3] = f2bf(fmaxf(ei00.w + ej00.w, 0.f));
            b0[4] = f2bf(fmaxf(ei01.x + ej01.x, 0.f));
            b0[5] = f2bf(fmaxf(ei01.y + ej01.y, 0.f));
            b0[6] = f2bf(fmaxf(ei01.z + ej01.z, 0.f));
            b0[7] = f2bf(fmaxf(ei01.w + ej01.w, 0.f));
            b1v[0] = f2bf(fmaxf(ei10.x + ej10.x, 0.f));
            b1v[1] = f2bf(fmaxf(ei10.y + ej10.y, 0.f));
            b1v[2] = f2bf(fmaxf(ei10.z + ej10.z, 0.f));
            b1v[3] = f2bf(fmaxf(ei10.w + ej10.w, 0.f));
            b1v[4] = f2bf(fmaxf(ei11.x + ej11.x, 0.f));
            b1v[5] = f2bf(fmaxf(ei11.y + ej11.y, 0.f));
            b1v[6] = f2bf(fmaxf(ei11.z + ej11.z, 0.f));
            b1v[7] = f2bf(fmaxf(ei11.w + ej11.w, 0.f));

            f32x4 acc0 = {0.f, 0.f, 0.f, 0.f};
            f32x4 acc1 = {0.f, 0.f, 0.f, 0.f};
            acc0 = __builtin_amdgcn_mfma_f32_16x16x32_bf16(aE00, b0,  acc0, 0, 0, 0);
            acc0 = __builtin_amdgcn_mfma_f32_16x16x32_bf16(aE10, b1v, acc0, 0, 0, 0);
            acc1 = __builtin_amdgcn_mfma_f32_16x16x32_bf16(aE01, b0,  acc1, 0, 0, 0);
            acc1 = __builtin_amdgcn_mfma_f32_16x16x32_bf16(aE11, b1v, acc1, 0, 0, 0);

            float pe = 0.f;
#pragma unroll
            for (int q = 0; q < 4; ++q) {
                const int k0 = 4 * g + q;
                pe += fmaxf(acc0[q] + bE2s[k0], 0.f) * E3s[k0];
                pe += fmaxf(acc1[q] + bE2s[k0 + 16], 0.f) * E3s[k0 + 16];
            }
            pe += __shfl_xor(pe, 16);
            pe += __shfl_xor(pe, 32);

            if (l < 16) {
                const float z = pe + bE3v;
                const float p = 1.0f / (1.0f + __expf(-z));
                const float av = (j == ig || !(p > 0.3f)) ? 0.f : p;
                out_adj[(size_t)b * 4096 + (size_t)ig * 64 + j] = av;
            }
        }
    }

    // ---- S pass (VALU): lane layout jl = l&15 (16 sj rows, 2-way free) ----
    {
        const int jl = l & 15, isub = l >> 4;
        for (int jt = 0; jt < 4; ++jt) {
            const int j = jt * 16 + jl;
            float4 sj4[8];
#pragma unroll
            for (int k8 = 0; k8 < 8; ++k8)
                sj4[k8] = *(const float4*)&sjR[j * SI2_S + 4 * k8];
#pragma unroll
            for (int ii = 0; ii < 4; ++ii) {
                const int ig = 16 * w + 4 * ii + isub;
                float sacc = 0.f;
#pragma unroll
                for (int k8 = 0; k8 < 8; ++k8) {
                    const float4 si4 = *(const float4*)&siR[ig * SI2_S + 4 * k8];
                    const float4 s24 = *(const float4*)&S2s[4 * k8];
                    sacc = fmaf(fmaxf(si4.x + sj4[k8].x, 0.f), s24.x, sacc);
                    sacc = fmaf(fmaxf(si4.y + sj4[k8].y, 0.f), s24.y, sacc);
                    sacc = fmaf(fmaxf(si4.z + sj4[k8].z, 0.f), s24.z, sacc);
                    sacc = fmaf(fmaxf(si4.w + sj4[k8].w, 0.f), s24.w, sacc);
                }
                const float xs = sacc + bS2v;
                const float e2x = __expf(2.0f * xs);
                const float sv = (j == ig) ? 0.f : (e2x - 1.0f) / (e2x + 1.0f);
                out_str[(size_t)b * 4096 + (size_t)ig * 64 + j] = sv;
            }
        }
    }
}

extern "C" void kernel_launch(void* const* d_in, const int* in_sizes, int n_in,
                              void* d_out, int out_size, void* d_ws, size_t ws_size,
                              hipStream_t stream)
{
    const float* x     = (const float*)d_in[0];
    const float* W1    = (const float*)d_in[1];
    const float* b1    = (const float*)d_in[2];
    const float* W2    = (const float*)d_in[3];
    const float* b2    = (const float*)d_in[4];
    const float* gamma = (const float*)d_in[5];
    const float* beta  = (const float*)d_in[6];
    const float* E1    = (const float*)d_in[7];
    const float* bE1   = (const float*)d_in[8];
    const float* E2    = (const float*)d_in[9];
    const float* bE2   = (const float*)d_in[10];
    const float* E3    = (const float*)d_in[11];
    const float* bE3   = (const float*)d_in[12];
    const float* S1    = (const float*)d_in[13];
    const float* bS1   = (const float*)d_in[14];
    const float* S2    = (const float*)d_in[15];
    const float* bS2   = (const float*)d_in[16];

    float* out     = (float*)d_out;
    float* out_nf  = out;                // 256*64*64
    float* out_adj = out + 1048576;
    float* out_str = out + 2097152;

    short* wT = (short*)d_ws;            // 104 KB of scratch, rewritten every call

    kernelA0<<<64, 256, 0, stream>>>(W1, W2, E1, S1, wT);

    kernelF<<<256, 256, 0, stream>>>(
        x, b1, b2, gamma, beta, wT,
        bE1, E2, bE2, E3, bE3, bS1, S2, bS2,
        out_nf, out_adj, out_str);
}

// Round 8
// 56.828 us; speedup vs baseline: 1.0003x; 1.0003x over previous
//
#include <hip/hip_runtime.h>
#include <hip/hip_bf16.h>
#include <math.h>

typedef __attribute__((ext_vector_type(8))) short short8;
typedef __attribute__((ext_vector_type(4))) short short4v;
typedef __attribute__((ext_vector_type(4))) float f32x4;

__device__ __forceinline__ short f2bf(float f) {
    __hip_bfloat16 h = __float2bfloat16(f);   // RNE; pairs fuse to v_cvt_pk_bf16_f32
    return __builtin_bit_cast(short, h);
}

// ============================================================================
// Kernel A0: one-time weight transpose + bf16 convert into d_ws.
// wT layout (shorts): W1T [128n][256k] @0 | W2T [64n][128k] @32768 |
//                     WcatT [192o][64k] @40960  (Wcat = [E1a|E1b|S1a|S1b])
// ============================================================================
__global__ __launch_bounds__(256)
void kernelA0(const float* __restrict__ W1, const float* __restrict__ W2,
              const float* __restrict__ E1, const float* __restrict__ S1,
              short* __restrict__ wT)
{
    const int tid = blockIdx.x * 256 + threadIdx.x;   // 64*256 = 16384
#pragma unroll
    for (int i = 0; i < 2; ++i) {                     // W1T: 32768 elems
        const int e = tid * 2 + i;
        const int n = e >> 8, k = e & 255;
        wT[e] = f2bf(W1[(size_t)k * 128 + n]);
    }
    if (tid < 8192) {                                 // W2T
        const int n = tid >> 7, k = tid & 127;
        wT[32768 + tid] = f2bf(W2[(size_t)k * 64 + n]);
    }
    if (tid < 12288) {                                // WcatT
        const int o = tid >> 6, k = tid & 63;
        float v;
        if (o < 64)       v = E1[(size_t)k * 64 + o];
        else if (o < 128) v = E1[(size_t)(64 + k) * 64 + (o - 64)];
        else if (o < 160) v = S1[(size_t)k * 32 + (o - 128)];
        else              v = S1[(size_t)(64 + k) * 32 + (o - 160)];
        wT[40960 + tid] = f2bf(v);
    }
}

// ============================================================================
// Kernel N (round 8): node path, ROW-PARALLEL. Grid (4 rowgroups, 256 batches)
// = 1024 blocks, 16 node-rows each -> 4 blocks/CU x 4 waves = 4 waves/SIMD
// (round 7 fused ran 1 wave/SIMD, Occupancy 9.6% -> latency-bound).
// MFMA lane mapping HW-validated rounds 4-7:
//   A[row=l&15][k=8*(l>>4)+e], B[k=8*(l>>4)+e][col=l&15], D[row=4*(l>>4)+q][col=l&15].
// ============================================================================
constexpr int NH1_S = 144;  // shorts (h1 bf16, 16 rows)
constexpr int NHS_S = 68;   // floats (h f32)
constexpr int NNF_S = 80;   // shorts (nf bf16)

__global__ __launch_bounds__(256, 2)
void kernelN(const float* __restrict__ x,
             const float* __restrict__ b1, const float* __restrict__ b2,
             const float* __restrict__ gamma, const float* __restrict__ beta,
             const short* __restrict__ wT,
             const float* __restrict__ bE1, const float* __restrict__ bS1,
             float* __restrict__ out_nf,
             float* __restrict__ ws_ei, float* __restrict__ ws_ej,
             float* __restrict__ ws_si, float* __restrict__ ws_sj)
{
    __shared__ short h1B[16 * NH1_S];   // 4.6 KB
    __shared__ float Hs [16 * NHS_S];   // 4.4 KB
    __shared__ short nfB[16 * NNF_S];   // 2.6 KB  (~11.5 KB total)

    const int t  = threadIdx.x;
    const int rg = blockIdx.x;          // row-group: rows 16rg..16rg+15
    const int b  = blockIdx.y;
    const int w  = t >> 6, l = t & 63, g = l >> 4, r = l & 15;
    const short* W1T = wT;
    const short* W2T = wT + 32768;
    const short* WcT = wT + 40960;

    // ---- A-frags: gathered X rows (all 4 waves load same 16 rows; L1 hit) ----
    const int mrow = 16 * rg + r;
    const int srow = (mrow == 63) ? 127 : (int)((float)mrow * (127.0f / 63.0f));
    const float* xrow = x + ((size_t)b * 128 + srow) * 256;
    short8 aX[8];
#pragma unroll
    for (int ks = 0; ks < 8; ++ks) {
        const float4 v0 = *(const float4*)(xrow + 32 * ks + 8 * g);
        const float4 v1 = *(const float4*)(xrow + 32 * ks + 8 * g + 4);
        short8 a;
        a[0] = f2bf(v0.x); a[1] = f2bf(v0.y); a[2] = f2bf(v0.z); a[3] = f2bf(v0.w);
        a[4] = f2bf(v1.x); a[5] = f2bf(v1.y); a[6] = f2bf(v1.z); a[7] = f2bf(v1.w);
        aX[ks] = a;
    }

    // ---- phase 2: h1[16][128] = relu(X@W1+b1); wave w covers cols 32w..32w+31 ----
#pragma unroll
    for (int nt2 = 0; nt2 < 2; ++nt2) {
        const int n = 32 * w + 16 * nt2 + r;
        f32x4 acca = {0.f, 0.f, 0.f, 0.f};
        f32x4 accb = {0.f, 0.f, 0.f, 0.f};
#pragma unroll
        for (int ks = 0; ks < 4; ++ks) {
            const short8 bwa = *(const short8*)(W1T + (size_t)n * 256 + 32 * ks + 8 * g);
            const short8 bwb = *(const short8*)(W1T + (size_t)n * 256 + 32 * (ks + 4) + 8 * g);
            acca = __builtin_amdgcn_mfma_f32_16x16x32_bf16(aX[ks],     bwa, acca, 0, 0, 0);
            accb = __builtin_amdgcn_mfma_f32_16x16x32_bf16(aX[ks + 4], bwb, accb, 0, 0, 0);
        }
        const float b1v = b1[n];
#pragma unroll
        for (int q = 0; q < 4; ++q)
            h1B[(4 * g + q) * NH1_S + n] = f2bf(fmaxf(acca[q] + accb[q] + b1v, 0.f));
    }
    __syncthreads();

    // ---- phase 3: h[16][64] = h1@W2+b2; wave w covers cols 16w..16w+15 ----
    {
        short8 ha[4];
#pragma unroll
        for (int ks = 0; ks < 4; ++ks)
            ha[ks] = *(const short8*)(&h1B[r * NH1_S + 32 * ks + 8 * g]);
        const int n = 16 * w + r;
        f32x4 acca = {0.f, 0.f, 0.f, 0.f};
        f32x4 accb = {0.f, 0.f, 0.f, 0.f};
        {
            const short8 bw0 = *(const short8*)(W2T + (size_t)n * 128 + 8 * g);
            const short8 bw1 = *(const short8*)(W2T + (size_t)n * 128 + 32 + 8 * g);
            const short8 bw2 = *(const short8*)(W2T + (size_t)n * 128 + 64 + 8 * g);
            const short8 bw3 = *(const short8*)(W2T + (size_t)n * 128 + 96 + 8 * g);
            acca = __builtin_amdgcn_mfma_f32_16x16x32_bf16(ha[0], bw0, acca, 0, 0, 0);
            accb = __builtin_amdgcn_mfma_f32_16x16x32_bf16(ha[1], bw1, accb, 0, 0, 0);
            acca = __builtin_amdgcn_mfma_f32_16x16x32_bf16(ha[2], bw2, acca, 0, 0, 0);
            accb = __builtin_amdgcn_mfma_f32_16x16x32_bf16(ha[3], bw3, accb, 0, 0, 0);
        }
        const float b2v = b2[n];
#pragma unroll
        for (int q = 0; q < 4; ++q)
            Hs[(4 * g + q) * NHS_S + n] = acca[q] + accb[q] + b2v;
    }
    __syncthreads();

    // ---- phase 4: LayerNorm; row = t>>4 (16 lanes/row, 4 cols/lane) ----
    {
        const int row = t >> 4, c4 = (t & 15) * 4;
        const float4 v = *(const float4*)&Hs[row * NHS_S + c4];
        float s = v.x + v.y + v.z + v.w;
        s += __shfl_xor(s, 1); s += __shfl_xor(s, 2);
        s += __shfl_xor(s, 4); s += __shfl_xor(s, 8);
        const float mu = s * (1.0f / 64.0f);
        float vs = 0.f;
        { const float d0 = v.x-mu, d1 = v.y-mu, d2 = v.z-mu, d3 = v.w-mu;
          vs = fmaf(d0,d0, fmaf(d1,d1, fmaf(d2,d2, d3*d3))); }
        vs += __shfl_xor(vs, 1); vs += __shfl_xor(vs, 2);
        vs += __shfl_xor(vs, 4); vs += __shfl_xor(vs, 8);
        const float rstd = rsqrtf(vs * (1.0f / 64.0f) + 1e-5f);
        const float4 gv = *(const float4*)(gamma + c4);
        const float4 bv = *(const float4*)(beta  + c4);
        float4 o;
        o.x = fmaf((v.x - mu) * rstd, gv.x, bv.x);
        o.y = fmaf((v.y - mu) * rstd, gv.y, bv.y);
        o.z = fmaf((v.z - mu) * rstd, gv.z, bv.z);
        o.w = fmaf((v.w - mu) * rstd, gv.w, bv.w);
        *(float4*)(out_nf + (size_t)b * 4096 + (size_t)(16 * rg + row) * 64 + c4) = o;
        short4v ob;
        ob[0] = f2bf(o.x); ob[1] = f2bf(o.y); ob[2] = f2bf(o.z); ob[3] = f2bf(o.w);
        *(short4v*)&nfB[row * NNF_S + c4] = ob;
    }
    __syncthreads();

    // ---- phase 5: [ei|ej|si|sj] = nf@Wcat; wave w covers o-tiles 3w..3w+2 ----
    const short8 na0 = *(const short8*)(&nfB[r * NNF_S + 8 * g]);
    const short8 na1 = *(const short8*)(&nfB[r * NNF_S + 32 + 8 * g]);
#pragma unroll
    for (int k3 = 0; k3 < 3; ++k3) {
        const int nt = 3 * w + k3;
        const int c = 16 * nt + r;
        const short8 bw0 = *(const short8*)(WcT + (size_t)c * 64 + 8 * g);
        const short8 bw1 = *(const short8*)(WcT + (size_t)c * 64 + 32 + 8 * g);
        f32x4 acc = {0.f, 0.f, 0.f, 0.f};
        acc = __builtin_amdgcn_mfma_f32_16x16x32_bf16(na0, bw0, acc, 0, 0, 0);
        acc = __builtin_amdgcn_mfma_f32_16x16x32_bf16(na1, bw1, acc, 0, 0, 0);
        float* dst; int cc, rs; float badd = 0.f;
        if (nt < 4)       { dst = ws_ei + (size_t)b * 4096; cc = c;       rs = 64; badd = bE1[c]; }
        else if (nt < 8)  { dst = ws_ej + (size_t)b * 4096; cc = c - 64;  rs = 64; }
        else if (nt < 10) { dst = ws_si + (size_t)b * 2048; cc = c - 128; rs = 32; badd = bS1[c - 128]; }
        else              { dst = ws_sj + (size_t)b * 2048; cc = c - 160; rs = 32; }
#pragma unroll
        for (int q = 0; q < 4; ++q)
            dst[(size_t)(16 * rg + 4 * g + q) * rs + cc] = acc[q] + badd;
    }
}

// ============================================================================
// Kernel B (round 8 = round 5 + cvt_pk f2bf + 2-way-conflict S-pass layout).
// ei/si arrive with biases already folded (kernelN).
// ============================================================================
constexpr int EJ_S = 76;
constexpr int EI_S = 68;
constexpr int SJ_S = 36;
constexpr int SI_S = 36;

__global__ __launch_bounds__(256, 2)
void kernelB(const float* __restrict__ ws_ei, const float* __restrict__ ws_ej,
             const float* __restrict__ ws_si, const float* __restrict__ ws_sj,
             const float* __restrict__ E2,
             const float* __restrict__ bE2, const float* __restrict__ E3,
             const float* __restrict__ bE3,
             const float* __restrict__ S2, const float* __restrict__ bS2,
             float* __restrict__ out_adj, float* __restrict__ out_str)
{
    __shared__ float ejR[64 * EJ_S];
    __shared__ float eis[16 * EI_S];
    __shared__ float sjR[64 * SJ_S];
    __shared__ float siR[16 * SI_S];
    __shared__ float bE2s[32], E3s[32], S2s[32];

    const int t  = threadIdx.x;
    const int qi = blockIdx.x;         // i-strip (16 rows)
    const int b  = blockIdx.y;
    const int w  = t >> 6, l = t & 63;
    const int g  = l >> 4, r = l & 15;

#pragma unroll
    for (int it = 0; it < 16; ++it) {  // ejR: 4096
        const int f = t + 256 * it; const int j = f >> 6, h = f & 63;
        ejR[j * EJ_S + h] = ws_ej[(size_t)b * 4096 + (size_t)j * 64 + h];
    }
#pragma unroll
    for (int it = 0; it < 4; ++it) {   // eis: 1024 (bias pre-folded)
        const int f = t + 256 * it; const int rr = f >> 6, h = f & 63;
        eis[rr * EI_S + h] = ws_ei[(size_t)b * 4096 + (size_t)(qi * 16 + rr) * 64 + h];
    }
#pragma unroll
    for (int it = 0; it < 8; ++it) {   // sjR: 2048
        const int f = t + 256 * it; const int j = f >> 5, k = f & 31;
        sjR[j * SJ_S + k] = ws_sj[(size_t)b * 2048 + (size_t)j * 32 + k];
    }
#pragma unroll
    for (int it = 0; it < 2; ++it) {   // siR: 512 (bias pre-folded)
        const int f = t + 256 * it; const int rr = f >> 5, k = f & 31;
        siR[rr * SI_S + k] = ws_si[(size_t)b * 2048 + (size_t)(qi * 16 + rr) * 32 + k];
    }
    if (t < 32)       bE2s[t] = bE2[t];
    else if (t < 64)  E3s[t - 32] = E3[t - 32];
    else if (t < 96)  S2s[t - 64] = S2[t - 64];

    short8 aE00, aE10, aE01, aE11;
#pragma unroll
    for (int e = 0; e < 8; ++e) {
        aE00[e] = f2bf(E2[(size_t)(8 * g + e) * 32 + r]);
        aE10[e] = f2bf(E2[(size_t)(8 * g + e + 32) * 32 + r]);
        aE01[e] = f2bf(E2[(size_t)(8 * g + e) * 32 + r + 16]);
        aE11[e] = f2bf(E2[(size_t)(8 * g + e + 32) * 32 + r + 16]);
    }
    const float bE3v = bE3[0], bS2v = bS2[0];
    __syncthreads();

    // ---- E pass: wave w owns i-rows 4w..4w+3; j-tiles 0..3 ----
    for (int jt = 0; jt < 4; ++jt) {
        const int j = (jt << 4) + r;
        const float4 ej00 = *(const float4*)&ejR[j * EJ_S + 8 * g];
        const float4 ej01 = *(const float4*)&ejR[j * EJ_S + 8 * g + 4];
        const float4 ej10 = *(const float4*)&ejR[j * EJ_S + 32 + 8 * g];
        const float4 ej11 = *(const float4*)&ejR[j * EJ_S + 32 + 8 * g + 4];

#pragma unroll
        for (int ii = 0; ii < 4; ++ii) {
            const int il = 4 * w + ii;
            const int ig = qi * 16 + il;
            const float4 ei00 = *(const float4*)&eis[il * EI_S + 8 * g];
            const float4 ei01 = *(const float4*)&eis[il * EI_S + 8 * g + 4];
            const float4 ei10 = *(const float4*)&eis[il * EI_S + 32 + 8 * g];
            const float4 ei11 = *(const float4*)&eis[il * EI_S + 32 + 8 * g + 4];

            short8 b0, b1v;
            b0[0] = f2bf(fmaxf(ei00.x + ej00.x, 0.f));
            b0[1] = f2bf(fmaxf(ei00.y + ej00.y, 0.f));
            b0[2] = f2bf(fmaxf(ei00.z + ej00.z, 0.f));
            b0[3] = f2bf(fmaxf(ei00.w + ej00.w, 0.f));
            b0[4] = f2bf(fmaxf(ei01.x + ej01.x, 0.f));
            b0[5] = f2bf(fmaxf(ei01.y + ej01.y, 0.f));
            b0[6] = f2bf(fmaxf(ei01.z + ej01.z, 0.f));
            b0[7] = f2bf(fmaxf(ei01.w + ej01.w, 0.f));
            b1v[0] = f2bf(fmaxf(ei10.x + ej10.x, 0.f));
            b1v[1] = f2bf(fmaxf(ei10.y + ej10.y, 0.f));
            b1v[2] = f2bf(fmaxf(ei10.z + ej10.z, 0.f));
            b1v[3] = f2bf(fmaxf(ei10.w + ej10.w, 0.f));
            b1v[4] = f2bf(fmaxf(ei11.x + ej11.x, 0.f));
            b1v[5] = f2bf(fmaxf(ei11.y + ej11.y, 0.f));
            b1v[6] = f2bf(fmaxf(ei11.z + ej11.z, 0.f));
            b1v[7] = f2bf(fmaxf(ei11.w + ej11.w, 0.f));

            f32x4 acc0 = {0.f, 0.f, 0.f, 0.f};
            f32x4 acc1 = {0.f, 0.f, 0.f, 0.f};
            acc0 = __builtin_amdgcn_mfma_f32_16x16x32_bf16(aE00, b0,  acc0, 0, 0, 0);
            acc0 = __builtin_amdgcn_mfma_f32_16x16x32_bf16(aE10, b1v, acc0, 0, 0, 0);
            acc1 = __builtin_amdgcn_mfma_f32_16x16x32_bf16(aE01, b0,  acc1, 0, 0, 0);
            acc1 = __builtin_amdgcn_mfma_f32_16x16x32_bf16(aE11, b1v, acc1, 0, 0, 0);

            float pe = 0.f;
#pragma unroll
            for (int q = 0; q < 4; ++q) {
                const int k0 = 4 * g + q;
                pe += fmaxf(acc0[q] + bE2s[k0], 0.f) * E3s[k0];
                pe += fmaxf(acc1[q] + bE2s[k0 + 16], 0.f) * E3s[k0 + 16];
            }
            pe += __shfl_xor(pe, 16);
            pe += __shfl_xor(pe, 32);

            if (l < 16) {
                const float z = pe + bE3v;
                const float p = 1.0f / (1.0f + __expf(-z));
                const float av = (j == ig || !(p > 0.3f)) ? 0.f : p;
                out_adj[(size_t)b * 4096 + (size_t)ig * 64 + j] = av;
            }
        }
    }

    // ---- S pass (VALU): wave w owns j = 16w+jl; lanes split i 4-ways ----
    {
        const int jl = l & 15, isub = l >> 4;
        const int j = 16 * w + jl;
        float4 sj4[8];
#pragma unroll
        for (int k8 = 0; k8 < 8; ++k8)
            sj4[k8] = *(const float4*)&sjR[j * SJ_S + 4 * k8];
#pragma unroll
        for (int ii = 0; ii < 4; ++ii) {
            const int il = 4 * ii + isub;
            const int ig = qi * 16 + il;
            float sacc = 0.f;
#pragma unroll
            for (int k8 = 0; k8 < 8; ++k8) {
                const float4 si4 = *(const float4*)&siR[il * SI_S + 4 * k8];
                const float4 s24 = *(const float4*)&S2s[4 * k8];
                sacc = fmaf(fmaxf(si4.x + sj4[k8].x, 0.f), s24.x, sacc);
                sacc = fmaf(fmaxf(si4.y + sj4[k8].y, 0.f), s24.y, sacc);
                sacc = fmaf(fmaxf(si4.z + sj4[k8].z, 0.f), s24.z, sacc);
                sacc = fmaf(fmaxf(si4.w + sj4[k8].w, 0.f), s24.w, sacc);
            }
            const float xs = sacc + bS2v;
            const float e2x = __expf(2.0f * xs);
            const float sv = (j == ig) ? 0.f : (e2x - 1.0f) / (e2x + 1.0f);
            out_str[(size_t)b * 4096 + (size_t)ig * 64 + j] = sv;
        }
    }
}

extern "C" void kernel_launch(void* const* d_in, const int* in_sizes, int n_in,
                              void* d_out, int out_size, void* d_ws, size_t ws_size,
                              hipStream_t stream)
{
    const float* x     = (const float*)d_in[0];
    const float* W1    = (const float*)d_in[1];
    const float* b1    = (const float*)d_in[2];
    const float* W2    = (const float*)d_in[3];
    const float* b2    = (const float*)d_in[4];
    const float* gamma = (const float*)d_in[5];
    const float* beta  = (const float*)d_in[6];
    const float* E1    = (const float*)d_in[7];
    const float* bE1   = (const float*)d_in[8];
    const float* E2    = (const float*)d_in[9];
    const float* bE2   = (const float*)d_in[10];
    const float* E3    = (const float*)d_in[11];
    const float* bE3   = (const float*)d_in[12];
    const float* S1    = (const float*)d_in[13];
    const float* bS1   = (const float*)d_in[14];
    const float* S2    = (const float*)d_in[15];
    const float* bS2   = (const float*)d_in[16];

    float* out     = (float*)d_out;
    float* out_nf  = out;                // 256*64*64
    float* out_adj = out + 1048576;
    float* out_str = out + 2097152;

    // d_ws layout: wT (104 KB, shorts) | ei 4MB | ej 4MB | si 2MB | sj 2MB
    short* wT    = (short*)d_ws;
    float* wsf   = (float*)d_ws;
    float* ws_ei = wsf + 32768;          // 128 KB offset
    float* ws_ej = ws_ei + 1048576;
    float* ws_si = ws_ej + 1048576;
    float* ws_sj = ws_si + 524288;

    kernelA0<<<64, 256, 0, stream>>>(W1, W2, E1, S1, wT);

    kernelN<<<dim3(4, 256), 256, 0, stream>>>(
        x, b1, b2, gamma, beta, wT, bE1, bS1,
        out_nf, ws_ei, ws_ej, ws_si, ws_sj);

    kernelB<<<dim3(4, 256), 256, 0, stream>>>(
        ws_ei, ws_ej, ws_si, ws_sj,
        E2, bE2, E3, bE3, S2, bS2,
        out_adj, out_str);
}

// Round 9
// 52.846 us; speedup vs baseline: 1.0757x; 1.0753x over previous
//
#include <hip/hip_runtime.h>
#include <hip/hip_bf16.h>
#include <math.h>

typedef __attribute__((ext_vector_type(8))) short short8;
typedef __attribute__((ext_vector_type(4))) short short4v;
typedef __attribute__((ext_vector_type(4))) float f32x4;
typedef __attribute__((ext_vector_type(2))) _Float16 h2;
typedef __attribute__((ext_vector_type(4))) _Float16 h4;
typedef __attribute__((ext_vector_type(8))) _Float16 h8;

__device__ __forceinline__ short f2bf(float f) {
    __hip_bfloat16 h = __float2bfloat16(f);   // RNE; pairs fuse to v_cvt_pk_bf16_f32
    return __builtin_bit_cast(short, h);
}

// ============================================================================
// Kernel A0 (unchanged): one-time weight transpose + bf16 convert into d_ws.
// wT layout (shorts): W1T [128n][256k] @0 | W2T [64n][128k] @32768 |
//                     WcatT [192o][64k] @40960  (Wcat = [E1a|E1b|S1a|S1b])
// ============================================================================
__global__ __launch_bounds__(256)
void kernelA0(const float* __restrict__ W1, const float* __restrict__ W2,
              const float* __restrict__ E1, const float* __restrict__ S1,
              short* __restrict__ wT)
{
    const int tid = blockIdx.x * 256 + threadIdx.x;   // 64*256 = 16384
#pragma unroll
    for (int i = 0; i < 2; ++i) {                     // W1T: 32768 elems
        const int e = tid * 2 + i;
        const int n = e >> 8, k = e & 255;
        wT[e] = f2bf(W1[(size_t)k * 128 + n]);
    }
    if (tid < 8192) {                                 // W2T
        const int n = tid >> 7, k = tid & 127;
        wT[32768 + tid] = f2bf(W2[(size_t)k * 64 + n]);
    }
    if (tid < 12288) {                                // WcatT
        const int o = tid >> 6, k = tid & 63;
        float v;
        if (o < 64)       v = E1[(size_t)k * 64 + o];
        else if (o < 128) v = E1[(size_t)(64 + k) * 64 + (o - 64)];
        else if (o < 160) v = S1[(size_t)k * 32 + (o - 128)];
        else              v = S1[(size_t)(64 + k) * 32 + (o - 160)];
        wT[40960 + tid] = f2bf(v);
    }
}

// ============================================================================
// Kernel N (unchanged from round 8): node path, row-parallel, 1024 blocks.
// ============================================================================
constexpr int NH1_S = 144;  // shorts (h1 bf16, 16 rows)
constexpr int NHS_S = 68;   // floats (h f32)
constexpr int NNF_S = 80;   // shorts (nf bf16)

__global__ __launch_bounds__(256, 2)
void kernelN(const float* __restrict__ x,
             const float* __restrict__ b1, const float* __restrict__ b2,
             const float* __restrict__ gamma, const float* __restrict__ beta,
             const short* __restrict__ wT,
             const float* __restrict__ bE1, const float* __restrict__ bS1,
             float* __restrict__ out_nf,
             float* __restrict__ ws_ei, float* __restrict__ ws_ej,
             float* __restrict__ ws_si, float* __restrict__ ws_sj)
{
    __shared__ short h1B[16 * NH1_S];
    __shared__ float Hs [16 * NHS_S];
    __shared__ short nfB[16 * NNF_S];

    const int t  = threadIdx.x;
    const int rg = blockIdx.x;
    const int b  = blockIdx.y;
    const int w  = t >> 6, l = t & 63, g = l >> 4, r = l & 15;
    const short* W1T = wT;
    const short* W2T = wT + 32768;
    const short* WcT = wT + 40960;

    const int mrow = 16 * rg + r;
    const int srow = (mrow == 63) ? 127 : (int)((float)mrow * (127.0f / 63.0f));
    const float* xrow = x + ((size_t)b * 128 + srow) * 256;
    short8 aX[8];
#pragma unroll
    for (int ks = 0; ks < 8; ++ks) {
        const float4 v0 = *(const float4*)(xrow + 32 * ks + 8 * g);
        const float4 v1 = *(const float4*)(xrow + 32 * ks + 8 * g + 4);
        short8 a;
        a[0] = f2bf(v0.x); a[1] = f2bf(v0.y); a[2] = f2bf(v0.z); a[3] = f2bf(v0.w);
        a[4] = f2bf(v1.x); a[5] = f2bf(v1.y); a[6] = f2bf(v1.z); a[7] = f2bf(v1.w);
        aX[ks] = a;
    }

#pragma unroll
    for (int nt2 = 0; nt2 < 2; ++nt2) {
        const int n = 32 * w + 16 * nt2 + r;
        f32x4 acca = {0.f, 0.f, 0.f, 0.f};
        f32x4 accb = {0.f, 0.f, 0.f, 0.f};
#pragma unroll
        for (int ks = 0; ks < 4; ++ks) {
            const short8 bwa = *(const short8*)(W1T + (size_t)n * 256 + 32 * ks + 8 * g);
            const short8 bwb = *(const short8*)(W1T + (size_t)n * 256 + 32 * (ks + 4) + 8 * g);
            acca = __builtin_amdgcn_mfma_f32_16x16x32_bf16(aX[ks],     bwa, acca, 0, 0, 0);
            accb = __builtin_amdgcn_mfma_f32_16x16x32_bf16(aX[ks + 4], bwb, accb, 0, 0, 0);
        }
        const float b1v = b1[n];
#pragma unroll
        for (int q = 0; q < 4; ++q)
            h1B[(4 * g + q) * NH1_S + n] = f2bf(fmaxf(acca[q] + accb[q] + b1v, 0.f));
    }
    __syncthreads();

    {
        short8 ha[4];
#pragma unroll
        for (int ks = 0; ks < 4; ++ks)
            ha[ks] = *(const short8*)(&h1B[r * NH1_S + 32 * ks + 8 * g]);
        const int n = 16 * w + r;
        f32x4 acca = {0.f, 0.f, 0.f, 0.f};
        f32x4 accb = {0.f, 0.f, 0.f, 0.f};
        {
            const short8 bw0 = *(const short8*)(W2T + (size_t)n * 128 + 8 * g);
            const short8 bw1 = *(const short8*)(W2T + (size_t)n * 128 + 32 + 8 * g);
            const short8 bw2 = *(const short8*)(W2T + (size_t)n * 128 + 64 + 8 * g);
            const short8 bw3 = *(const short8*)(W2T + (size_t)n * 128 + 96 + 8 * g);
            acca = __builtin_amdgcn_mfma_f32_16x16x32_bf16(ha[0], bw0, acca, 0, 0, 0);
            accb = __builtin_amdgcn_mfma_f32_16x16x32_bf16(ha[1], bw1, accb, 0, 0, 0);
            acca = __builtin_amdgcn_mfma_f32_16x16x32_bf16(ha[2], bw2, acca, 0, 0, 0);
            accb = __builtin_amdgcn_mfma_f32_16x16x32_bf16(ha[3], bw3, accb, 0, 0, 0);
        }
        const float b2v = b2[n];
#pragma unroll
        for (int q = 0; q < 4; ++q)
            Hs[(4 * g + q) * NHS_S + n] = acca[q] + accb[q] + b2v;
    }
    __syncthreads();

    {
        const int row = t >> 4, c4 = (t & 15) * 4;
        const float4 v = *(const float4*)&Hs[row * NHS_S + c4];
        float s = v.x + v.y + v.z + v.w;
        s += __shfl_xor(s, 1); s += __shfl_xor(s, 2);
        s += __shfl_xor(s, 4); s += __shfl_xor(s, 8);
        const float mu = s * (1.0f / 64.0f);
        float vs = 0.f;
        { const float d0 = v.x-mu, d1 = v.y-mu, d2 = v.z-mu, d3 = v.w-mu;
          vs = fmaf(d0,d0, fmaf(d1,d1, fmaf(d2,d2, d3*d3))); }
        vs += __shfl_xor(vs, 1); vs += __shfl_xor(vs, 2);
        vs += __shfl_xor(vs, 4); vs += __shfl_xor(vs, 8);
        const float rstd = rsqrtf(vs * (1.0f / 64.0f) + 1e-5f);
        const float4 gv = *(const float4*)(gamma + c4);
        const float4 bv = *(const float4*)(beta  + c4);
        float4 o;
        o.x = fmaf((v.x - mu) * rstd, gv.x, bv.x);
        o.y = fmaf((v.y - mu) * rstd, gv.y, bv.y);
        o.z = fmaf((v.z - mu) * rstd, gv.z, bv.z);
        o.w = fmaf((v.w - mu) * rstd, gv.w, bv.w);
        *(float4*)(out_nf + (size_t)b * 4096 + (size_t)(16 * rg + row) * 64 + c4) = o;
        short4v ob;
        ob[0] = f2bf(o.x); ob[1] = f2bf(o.y); ob[2] = f2bf(o.z); ob[3] = f2bf(o.w);
        *(short4v*)&nfB[row * NNF_S + c4] = ob;
    }
    __syncthreads();

    const short8 na0 = *(const short8*)(&nfB[r * NNF_S + 8 * g]);
    const short8 na1 = *(const short8*)(&nfB[r * NNF_S + 32 + 8 * g]);
#pragma unroll
    for (int k3 = 0; k3 < 3; ++k3) {
        const int nt = 3 * w + k3;
        const int c = 16 * nt + r;
        const short8 bw0 = *(const short8*)(WcT + (size_t)c * 64 + 8 * g);
        const short8 bw1 = *(const short8*)(WcT + (size_t)c * 64 + 32 + 8 * g);
        f32x4 acc = {0.f, 0.f, 0.f, 0.f};
        acc = __builtin_amdgcn_mfma_f32_16x16x32_bf16(na0, bw0, acc, 0, 0, 0);
        acc = __builtin_amdgcn_mfma_f32_16x16x32_bf16(na1, bw1, acc, 0, 0, 0);
        float* dst; int cc, rs; float badd = 0.f;
        if (nt < 4)       { dst = ws_ei + (size_t)b * 4096; cc = c;       rs = 64; badd = bE1[c]; }
        else if (nt < 8)  { dst = ws_ej + (size_t)b * 4096; cc = c - 64;  rs = 64; }
        else if (nt < 10) { dst = ws_si + (size_t)b * 2048; cc = c - 128; rs = 32; badd = bS1[c - 128]; }
        else              { dst = ws_sj + (size_t)b * 2048; cc = c - 160; rs = 32; }
#pragma unroll
        for (int q = 0; q < 4; ++q)
            dst[(size_t)(16 * rg + 4 * g + q) * rs + cc] = acc[q] + badd;
    }
}

// ============================================================================
// Kernel B v2 (round 9): packed-f16 edge/strength stage.
// he=relu(ei+ej) via v_pk_add_f16/v_pk_max_f16 (no per-iter cvt; cvt moved to
// staging). MFMA 16x16x32_f16 (same frag layout as bf16, HW-validated).
// S-dot via v_dot2_f32_f16. Cuts edge b-build VALU ~2.5x (the cost invariant
// across rounds 5-8) and removes round-8's 32-reg f32 sj hoist (spill risk).
// ============================================================================
constexpr int EJH = 34;   // h2 stride (68 halfs) for ei/ej rows
constexpr int SJH = 18;   // h2 stride (36 halfs) for si/sj rows

__global__ __launch_bounds__(256, 2)
void kernelB(const float* __restrict__ ws_ei, const float* __restrict__ ws_ej,
             const float* __restrict__ ws_si, const float* __restrict__ ws_sj,
             const float* __restrict__ E2,
             const float* __restrict__ bE2, const float* __restrict__ E3,
             const float* __restrict__ bE3,
             const float* __restrict__ S2, const float* __restrict__ bS2,
             float* __restrict__ out_adj, float* __restrict__ out_str)
{
    __shared__ h2 ejH[64 * EJH];   // 8.7 KB
    __shared__ h2 eiH[16 * EJH];   // 2.2 KB
    __shared__ h2 sjH[64 * SJH];   // 4.6 KB
    __shared__ h2 siH[16 * SJH];   // 1.2 KB
    __shared__ float bE2s[32], E3s[32];

    const int t  = threadIdx.x;
    const int qi = blockIdx.x;         // i-strip (16 rows)
    const int b  = blockIdx.y;
    const int w  = t >> 6, l = t & 63;
    const int g  = l >> 4, r = l & 15;

    // ---- stage (f32 -> f16 pairs; coalesced float2 reads) ----
#pragma unroll
    for (int it = 0; it < 8; ++it) {   // ejH: 2048 h2
        const int f = t + 256 * it; const int j = f >> 5, k2 = f & 31;
        const float2 v = *(const float2*)&ws_ej[(size_t)b * 4096 + (size_t)j * 64 + 2 * k2];
        h2 p; p[0] = (_Float16)v.x; p[1] = (_Float16)v.y;
        ejH[j * EJH + k2] = p;
    }
#pragma unroll
    for (int it = 0; it < 2; ++it) {   // eiH: 512 h2 (bias pre-folded by N)
        const int f = t + 256 * it; const int rr = f >> 5, k2 = f & 31;
        const float2 v = *(const float2*)&ws_ei[(size_t)b * 4096 + (size_t)(qi * 16 + rr) * 64 + 2 * k2];
        h2 p; p[0] = (_Float16)v.x; p[1] = (_Float16)v.y;
        eiH[rr * EJH + k2] = p;
    }
#pragma unroll
    for (int it = 0; it < 4; ++it) {   // sjH: 1024 h2
        const int f = t + 256 * it; const int j = f >> 4, k2 = f & 15;
        const float2 v = *(const float2*)&ws_sj[(size_t)b * 2048 + (size_t)j * 32 + 2 * k2];
        h2 p; p[0] = (_Float16)v.x; p[1] = (_Float16)v.y;
        sjH[j * SJH + k2] = p;
    }
    {                                  // siH: 256 h2 (bias pre-folded)
        const int rr = t >> 4, k2 = t & 15;
        const float2 v = *(const float2*)&ws_si[(size_t)b * 2048 + (size_t)(qi * 16 + rr) * 32 + 2 * k2];
        h2 p; p[0] = (_Float16)v.x; p[1] = (_Float16)v.y;
        siH[rr * SJH + k2] = p;
    }
    if (t < 32)      bE2s[t] = bE2[t];
    else if (t < 64) E3s[t - 32] = E3[t - 32];

    // ---- A-frags: E2^T in f16 (mapping HW-validated rounds 4-8) ----
    h8 aE00, aE10, aE01, aE11;
#pragma unroll
    for (int e = 0; e < 8; ++e) {
        aE00[e] = (_Float16)E2[(size_t)(8 * g + e) * 32 + r];
        aE10[e] = (_Float16)E2[(size_t)(8 * g + e + 32) * 32 + r];
        aE01[e] = (_Float16)E2[(size_t)(8 * g + e) * 32 + r + 16];
        aE11[e] = (_Float16)E2[(size_t)(8 * g + e + 32) * 32 + r + 16];
    }
    h4 s2h[8];                         // S2 in f16 pairs for fdot2
#pragma unroll
    for (int q8 = 0; q8 < 8; ++q8) {
        h4 p;
        p[0] = (_Float16)S2[4 * q8];     p[1] = (_Float16)S2[4 * q8 + 1];
        p[2] = (_Float16)S2[4 * q8 + 2]; p[3] = (_Float16)S2[4 * q8 + 3];
        s2h[q8] = p;
    }
    const float bE3v = bE3[0], bS2v = bS2[0];
    const h4 z4 = {(_Float16)0.f, (_Float16)0.f, (_Float16)0.f, (_Float16)0.f};
    __syncthreads();

    // ---- E pass: wave w owns i-rows 4w..4w+3; j-tiles 0..3 ----
    for (int jt = 0; jt < 4; ++jt) {
        const int j = (jt << 4) + r;
        const h4 ej0a = *(const h4*)&ejH[j * EJH + 4 * g];
        const h4 ej0b = *(const h4*)&ejH[j * EJH + 4 * g + 2];
        const h4 ej1a = *(const h4*)&ejH[j * EJH + 16 + 4 * g];
        const h4 ej1b = *(const h4*)&ejH[j * EJH + 16 + 4 * g + 2];

#pragma unroll
        for (int ii = 0; ii < 4; ++ii) {
            const int il = 4 * w + ii;
            const int ig = qi * 16 + il;
            // ei reads are wave-uniform (broadcast, conflict-free)
            const h4 ei0a = *(const h4*)&eiH[il * EJH + 4 * g];
            const h4 ei0b = *(const h4*)&eiH[il * EJH + 4 * g + 2];
            const h4 ei1a = *(const h4*)&eiH[il * EJH + 16 + 4 * g];
            const h4 ei1b = *(const h4*)&eiH[il * EJH + 16 + 4 * g + 2];

            const h4 he0a = __builtin_elementwise_max(ei0a + ej0a, z4);
            const h4 he0b = __builtin_elementwise_max(ei0b + ej0b, z4);
            const h4 he1a = __builtin_elementwise_max(ei1a + ej1a, z4);
            const h4 he1b = __builtin_elementwise_max(ei1b + ej1b, z4);
            const h8 b0 = __builtin_shufflevector(he0a, he0b, 0, 1, 2, 3, 4, 5, 6, 7);
            const h8 b1 = __builtin_shufflevector(he1a, he1b, 0, 1, 2, 3, 4, 5, 6, 7);

            f32x4 acc0 = {0.f, 0.f, 0.f, 0.f};
            f32x4 acc1 = {0.f, 0.f, 0.f, 0.f};
            acc0 = __builtin_amdgcn_mfma_f32_16x16x32_f16(aE00, b0, acc0, 0, 0, 0);
            acc0 = __builtin_amdgcn_mfma_f32_16x16x32_f16(aE10, b1, acc0, 0, 0, 0);
            acc1 = __builtin_amdgcn_mfma_f32_16x16x32_f16(aE01, b0, acc1, 0, 0, 0);
            acc1 = __builtin_amdgcn_mfma_f32_16x16x32_f16(aE11, b1, acc1, 0, 0, 0);

            float pe = 0.f;
#pragma unroll
            for (int q = 0; q < 4; ++q) {
                const int k0 = 4 * g + q;
                pe += fmaxf(acc0[q] + bE2s[k0], 0.f) * E3s[k0];
                pe += fmaxf(acc1[q] + bE2s[k0 + 16], 0.f) * E3s[k0 + 16];
            }
            pe += __shfl_xor(pe, 16);
            pe += __shfl_xor(pe, 32);

            if (l < 16) {
                const float z = pe + bE3v;
                const float p = 1.0f / (1.0f + __expf(-z));
                const float av = (j == ig || !(p > 0.3f)) ? 0.f : p;
                out_adj[(size_t)b * 4096 + (size_t)ig * 64 + j] = av;
            }
        }
    }

    // ---- S pass: packed f16 + fdot2; j = t&63, 4 i-rows per thread ----
    {
        const int j = t & 63;
        const int ib = (t >> 6) * 4;
        h4 sj4[8];                      // 16 VGPR (was 32 f32 in round 8)
#pragma unroll
        for (int q8 = 0; q8 < 8; ++q8)
            sj4[q8] = *(const h4*)&sjH[j * SJH + 2 * q8];
#pragma unroll
        for (int ii = 0; ii < 4; ++ii) {
            const int il = ib + ii;
            const int ig = qi * 16 + il;
            float sacc = 0.f;
#pragma unroll
            for (int q8 = 0; q8 < 8; ++q8) {
                const h4 si4 = *(const h4*)&siH[il * SJH + 2 * q8];   // broadcast
                const h4 hs = __builtin_elementwise_max(si4 + sj4[q8], z4);
                const h2 lo   = __builtin_shufflevector(hs, hs, 0, 1);
                const h2 hi   = __builtin_shufflevector(hs, hs, 2, 3);
                const h2 s2lo = __builtin_shufflevector(s2h[q8], s2h[q8], 0, 1);
                const h2 s2hi = __builtin_shufflevector(s2h[q8], s2h[q8], 2, 3);
                sacc = __builtin_amdgcn_fdot2(lo, s2lo, sacc, false);
                sacc = __builtin_amdgcn_fdot2(hi, s2hi, sacc, false);
            }
            const float xs = sacc + bS2v;
            const float e2x = __expf(2.0f * xs);
            const float sv = (j == ig) ? 0.f : (e2x - 1.0f) / (e2x + 1.0f);
            out_str[(size_t)b * 4096 + (size_t)ig * 64 + j] = sv;
        }
    }
}

extern "C" void kernel_launch(void* const* d_in, const int* in_sizes, int n_in,
                              void* d_out, int out_size, void* d_ws, size_t ws_size,
                              hipStream_t stream)
{
    const float* x     = (const float*)d_in[0];
    const float* W1    = (const float*)d_in[1];
    const float* b1    = (const float*)d_in[2];
    const float* W2    = (const float*)d_in[3];
    const float* b2    = (const float*)d_in[4];
    const float* gamma = (const float*)d_in[5];
    const float* beta  = (const float*)d_in[6];
    const float* E1    = (const float*)d_in[7];
    const float* bE1   = (const float*)d_in[8];
    const float* E2    = (const float*)d_in[9];
    const float* bE2   = (const float*)d_in[10];
    const float* E3    = (const float*)d_in[11];
    const float* bE3   = (const float*)d_in[12];
    const float* S1    = (const float*)d_in[13];
    const float* bS1   = (const float*)d_in[14];
    const float* S2    = (const float*)d_in[15];
    const float* bS2   = (const float*)d_in[16];

    float* out     = (float*)d_out;
    float* out_nf  = out;                // 256*64*64
    float* out_adj = out + 1048576;
    float* out_str = out + 2097152;

    // d_ws layout: wT (104 KB, shorts) | ei 4MB | ej 4MB | si 2MB | sj 2MB
    short* wT    = (short*)d_ws;
    float* wsf   = (float*)d_ws;
    float* ws_ei = wsf + 32768;          // 128 KB offset
    float* ws_ej = ws_ei + 1048576;
    float* ws_si = ws_ej + 1048576;
    float* ws_sj = ws_si + 524288;

    kernelA0<<<64, 256, 0, stream>>>(W1, W2, E1, S1, wT);

    kernelN<<<dim3(4, 256), 256, 0, stream>>>(
        x, b1, b2, gamma, beta, wT, bE1, bS1,
        out_nf, ws_ei, ws_ej, ws_si, ws_sj);

    kernelB<<<dim3(4, 256), 256, 0, stream>>>(
        ws_ei, ws_ej, ws_si, ws_sj,
        E2, bE2, E3, bE3, S2, bS2,
        out_adj, out_str);
}

// Round 10
// 45.805 us; speedup vs baseline: 1.2411x; 1.1537x over previous
//
#include <hip/hip_runtime.h>
#include <hip/hip_bf16.h>
#include <math.h>

typedef __attribute__((ext_vector_type(8))) short short8;
typedef __attribute__((ext_vector_type(4))) short short4v;
typedef __attribute__((ext_vector_type(4))) float f32x4;
typedef __attribute__((ext_vector_type(2))) _Float16 h2;
typedef __attribute__((ext_vector_type(4))) _Float16 h4;
typedef __attribute__((ext_vector_type(8))) _Float16 h8;

__device__ __forceinline__ short f2bf(float f) {
    __hip_bfloat16 h = __float2bfloat16(f);   // RNE; pairs fuse to v_cvt_pk_bf16_f32
    return __builtin_bit_cast(short, h);
}

// ============================================================================
// Kernel A0 v2: coalesced reads + scattered 2B writes (stores don't stall).
// Grid 128x256 = 32768 threads (was 64 blocks = 1 wave/CU -> 5us).
// wT layout (shorts): W1T [128n][256k] @0 | W2T [64n][128k] @32768 |
//                     WcatT [192o][64k] @40960  (Wcat = [E1a|E1b|S1a|S1b])
// ============================================================================
__global__ __launch_bounds__(256)
void kernelA0(const float* __restrict__ W1, const float* __restrict__ W2,
              const float* __restrict__ E1, const float* __restrict__ S1,
              short* __restrict__ wT)
{
    const int tid = blockIdx.x * 256 + threadIdx.x;   // 32768
    {   // W1 [256k][128n] -> W1T[n][k]
        const int k = tid >> 7, n = tid & 127;
        wT[n * 256 + k] = f2bf(W1[tid]);
    }
    if (tid < 8192) {   // W2 [128k][64n] -> W2T[n][k]
        const int k = tid >> 6, n = tid & 63;
        wT[32768 + n * 128 + k] = f2bf(W2[tid]);
    }
    if (tid < 8192) {   // E1 [128][64] -> WcatT cols 0..127
        const int rr = tid >> 6, c = tid & 63;
        const int o = (rr < 64) ? c : (64 + c);
        const int k = (rr < 64) ? rr : (rr - 64);
        wT[40960 + o * 64 + k] = f2bf(E1[tid]);
    }
    if (tid < 4096) {   // S1 [128][32] -> WcatT cols 128..191
        const int rr = tid >> 5, c = tid & 31;
        const int o = (rr < 64) ? (128 + c) : (160 + c);
        const int k = (rr < 64) ? rr : (rr - 64);
        wT[40960 + o * 64 + k] = f2bf(S1[tid]);
    }
}

// ============================================================================
// Kernel N v3: node path. X staged to LDS COALESCED in bf16 (kills the 16-way
// gather: was 16 transactions/load instr; frag build is now 1 ds_read_b128,
// no aX[8] register array). Bank-conflict-free strides (== 4 mod 32 dwords).
// MFMA mapping HW-validated rounds 4-9: A[row=l&15][k=8*(l>>4)+e],
// B[k=8*(l>>4)+e][col=l&15], D[row=4*(l>>4)+q][col=l&15].
// ============================================================================
constexpr int XS_S  = 264;  // shorts/row (132 dw, %32=4 -> 2-way free)
constexpr int NH1_S = 136;  // shorts (68 dw, %32=4 -> 2-way free)
constexpr int NHS_S = 68;   // floats (%32=4 -> 2-way free)
constexpr int NNF_S = 72;   // shorts (36 dw, %32=4 -> 2-way free)

__global__ __launch_bounds__(256, 2)
void kernelN(const float* __restrict__ x,
             const float* __restrict__ b1, const float* __restrict__ b2,
             const float* __restrict__ gamma, const float* __restrict__ beta,
             const short* __restrict__ wT,
             const float* __restrict__ bE1, const float* __restrict__ bS1,
             float* __restrict__ out_nf,
             float* __restrict__ ws_ei, float* __restrict__ ws_ej,
             float* __restrict__ ws_si, float* __restrict__ ws_sj)
{
    __shared__ short Xs [16 * XS_S];    // 8.3 KB (bf16 X rows)
    __shared__ short h1B[16 * NH1_S];   // 4.3 KB
    __shared__ float Hs [16 * NHS_S];   // 4.4 KB
    __shared__ short nfB[16 * NNF_S];   // 2.3 KB  (~19 KB total)

    const int t  = threadIdx.x;
    const int rg = blockIdx.x;          // rows 16rg..16rg+15
    const int b  = blockIdx.y;
    const int w  = t >> 6, l = t & 63, g = l >> 4, r = l & 15;
    const short* W1T = wT;
    const short* W2T = wT + 32768;
    const short* WcT = wT + 40960;

    // ---- stage X coalesced: 16 threads/row, contiguous float4, cvt to bf16 ----
    {
        const int row = t >> 4, c0 = t & 15;
        const int m = 16 * rg + row;
        const int srow = (m == 63) ? 127 : (int)((float)m * (127.0f / 63.0f));
        const float* xrow = x + ((size_t)b * 128 + srow) * 256;
#pragma unroll
        for (int i = 0; i < 4; ++i) {
            const int c4 = (c0 + 16 * i) * 4;
            const float4 v = *(const float4*)(xrow + c4);
            short4v s;
            s[0] = f2bf(v.x); s[1] = f2bf(v.y); s[2] = f2bf(v.z); s[3] = f2bf(v.w);
            *(short4v*)&Xs[row * XS_S + c4] = s;
        }
    }
    __syncthreads();

    // ---- phase 2: h1[16][128] = relu(X@W1+b1); wave w covers cols 32w..32w+31 ----
#pragma unroll
    for (int nt2 = 0; nt2 < 2; ++nt2) {
        const int n = 32 * w + 16 * nt2 + r;
        f32x4 acca = {0.f, 0.f, 0.f, 0.f};
        f32x4 accb = {0.f, 0.f, 0.f, 0.f};
#pragma unroll
        for (int ks = 0; ks < 4; ++ks) {
            const short8 a0  = *(const short8*)&Xs[r * XS_S + 32 * ks + 8 * g];
            const short8 a1  = *(const short8*)&Xs[r * XS_S + 32 * (ks + 4) + 8 * g];
            const short8 bwa = *(const short8*)(W1T + (size_t)n * 256 + 32 * ks + 8 * g);
            const short8 bwb = *(const short8*)(W1T + (size_t)n * 256 + 32 * (ks + 4) + 8 * g);
            acca = __builtin_amdgcn_mfma_f32_16x16x32_bf16(a0, bwa, acca, 0, 0, 0);
            accb = __builtin_amdgcn_mfma_f32_16x16x32_bf16(a1, bwb, accb, 0, 0, 0);
        }
        const float b1v = b1[n];
#pragma unroll
        for (int q = 0; q < 4; ++q)
            h1B[(4 * g + q) * NH1_S + n] = f2bf(fmaxf(acca[q] + accb[q] + b1v, 0.f));
    }
    __syncthreads();

    // ---- phase 3: h[16][64] = h1@W2+b2; wave w covers cols 16w..16w+15 ----
    {
        const int n = 16 * w + r;
        f32x4 acca = {0.f, 0.f, 0.f, 0.f};
        f32x4 accb = {0.f, 0.f, 0.f, 0.f};
#pragma unroll
        for (int ks2 = 0; ks2 < 2; ++ks2) {
            const short8 ha0 = *(const short8*)&h1B[r * NH1_S + 32 * (2 * ks2) + 8 * g];
            const short8 ha1 = *(const short8*)&h1B[r * NH1_S + 32 * (2 * ks2 + 1) + 8 * g];
            const short8 bw0 = *(const short8*)(W2T + (size_t)n * 128 + 32 * (2 * ks2) + 8 * g);
            const short8 bw1 = *(const short8*)(W2T + (size_t)n * 128 + 32 * (2 * ks2 + 1) + 8 * g);
            acca = __builtin_amdgcn_mfma_f32_16x16x32_bf16(ha0, bw0, acca, 0, 0, 0);
            accb = __builtin_amdgcn_mfma_f32_16x16x32_bf16(ha1, bw1, accb, 0, 0, 0);
        }
        const float b2v = b2[n];
#pragma unroll
        for (int q = 0; q < 4; ++q)
            Hs[(4 * g + q) * NHS_S + n] = acca[q] + accb[q] + b2v;
    }
    __syncthreads();

    // ---- phase 4: LayerNorm; row = t>>4 (16 lanes/row, 4 cols/lane) ----
    {
        const int row = t >> 4, c4 = (t & 15) * 4;
        const float4 v = *(const float4*)&Hs[row * NHS_S + c4];
        float s = v.x + v.y + v.z + v.w;
        s += __shfl_xor(s, 1); s += __shfl_xor(s, 2);
        s += __shfl_xor(s, 4); s += __shfl_xor(s, 8);
        const float mu = s * (1.0f / 64.0f);
        float vs = 0.f;
        { const float d0 = v.x-mu, d1 = v.y-mu, d2 = v.z-mu, d3 = v.w-mu;
          vs = fmaf(d0,d0, fmaf(d1,d1, fmaf(d2,d2, d3*d3))); }
        vs += __shfl_xor(vs, 1); vs += __shfl_xor(vs, 2);
        vs += __shfl_xor(vs, 4); vs += __shfl_xor(vs, 8);
        const float rstd = rsqrtf(vs * (1.0f / 64.0f) + 1e-5f);
        const float4 gv = *(const float4*)(gamma + c4);
        const float4 bv = *(const float4*)(beta  + c4);
        float4 o;
        o.x = fmaf((v.x - mu) * rstd, gv.x, bv.x);
        o.y = fmaf((v.y - mu) * rstd, gv.y, bv.y);
        o.z = fmaf((v.z - mu) * rstd, gv.z, bv.z);
        o.w = fmaf((v.w - mu) * rstd, gv.w, bv.w);
        *(float4*)(out_nf + (size_t)b * 4096 + (size_t)(16 * rg + row) * 64 + c4) = o;
        short4v ob;
        ob[0] = f2bf(o.x); ob[1] = f2bf(o.y); ob[2] = f2bf(o.z); ob[3] = f2bf(o.w);
        *(short4v*)&nfB[row * NNF_S + c4] = ob;
    }
    __syncthreads();

    // ---- phase 5: [ei|ej|si|sj] = nf@Wcat; wave w covers o-tiles 3w..3w+2 ----
    const short8 na0 = *(const short8*)&nfB[r * NNF_S + 8 * g];
    const short8 na1 = *(const short8*)&nfB[r * NNF_S + 32 + 8 * g];
#pragma unroll
    for (int k3 = 0; k3 < 3; ++k3) {
        const int nt = 3 * w + k3;
        const int c = 16 * nt + r;
        const short8 bw0 = *(const short8*)(WcT + (size_t)c * 64 + 8 * g);
        const short8 bw1 = *(const short8*)(WcT + (size_t)c * 64 + 32 + 8 * g);
        f32x4 acc = {0.f, 0.f, 0.f, 0.f};
        acc = __builtin_amdgcn_mfma_f32_16x16x32_bf16(na0, bw0, acc, 0, 0, 0);
        acc = __builtin_amdgcn_mfma_f32_16x16x32_bf16(na1, bw1, acc, 0, 0, 0);
        float* dst; int cc, rs; float badd = 0.f;
        if (nt < 4)       { dst = ws_ei + (size_t)b * 4096; cc = c;       rs = 64; badd = bE1[c]; }
        else if (nt < 8)  { dst = ws_ej + (size_t)b * 4096; cc = c - 64;  rs = 64; }
        else if (nt < 10) { dst = ws_si + (size_t)b * 2048; cc = c - 128; rs = 32; badd = bS1[c - 128]; }
        else              { dst = ws_sj + (size_t)b * 2048; cc = c - 160; rs = 32; }
#pragma unroll
        for (int q = 0; q < 4; ++q)
            dst[(size_t)(16 * rg + 4 * g + q) * rs + cc] = acc[q] + badd;
    }
}

// ============================================================================
// Kernel B v2.1 (round 10): packed-f16 edge/strength stage + ei-fragment hoist
// (ei is jt-invariant: was re-read from LDS 4x). S2/sj register loads moved
// after the E pass (shorter live ranges).
// ============================================================================
constexpr int EJH = 34;   // h2 stride (68 halfs)
constexpr int SJH = 18;   // h2 stride (36 halfs)

__global__ __launch_bounds__(256, 2)
void kernelB(const float* __restrict__ ws_ei, const float* __restrict__ ws_ej,
             const float* __restrict__ ws_si, const float* __restrict__ ws_sj,
             const float* __restrict__ E2,
             const float* __restrict__ bE2, const float* __restrict__ E3,
             const float* __restrict__ bE3,
             const float* __restrict__ S2, const float* __restrict__ bS2,
             float* __restrict__ out_adj, float* __restrict__ out_str)
{
    __shared__ h2 ejH[64 * EJH];   // 8.7 KB
    __shared__ h2 eiH[16 * EJH];   // 2.2 KB
    __shared__ h2 sjH[64 * SJH];   // 4.6 KB
    __shared__ h2 siH[16 * SJH];   // 1.2 KB
    __shared__ float bE2s[32], E3s[32];

    const int t  = threadIdx.x;
    const int qi = blockIdx.x;         // i-strip (16 rows)
    const int b  = blockIdx.y;
    const int w  = t >> 6, l = t & 63;
    const int g  = l >> 4, r = l & 15;

    // ---- stage (f32 -> f16 pairs; coalesced float2 reads) ----
#pragma unroll
    for (int it = 0; it < 8; ++it) {   // ejH: 2048 h2
        const int f = t + 256 * it; const int j = f >> 5, k2 = f & 31;
        const float2 v = *(const float2*)&ws_ej[(size_t)b * 4096 + (size_t)j * 64 + 2 * k2];
        h2 p; p[0] = (_Float16)v.x; p[1] = (_Float16)v.y;
        ejH[j * EJH + k2] = p;
    }
#pragma unroll
    for (int it = 0; it < 2; ++it) {   // eiH: 512 h2 (bias pre-folded by N)
        const int f = t + 256 * it; const int rr = f >> 5, k2 = f & 31;
        const float2 v = *(const float2*)&ws_ei[(size_t)b * 4096 + (size_t)(qi * 16 + rr) * 64 + 2 * k2];
        h2 p; p[0] = (_Float16)v.x; p[1] = (_Float16)v.y;
        eiH[rr * EJH + k2] = p;
    }
#pragma unroll
    for (int it = 0; it < 4; ++it) {   // sjH: 1024 h2
        const int f = t + 256 * it; const int j = f >> 4, k2 = f & 15;
        const float2 v = *(const float2*)&ws_sj[(size_t)b * 2048 + (size_t)j * 32 + 2 * k2];
        h2 p; p[0] = (_Float16)v.x; p[1] = (_Float16)v.y;
        sjH[j * SJH + k2] = p;
    }
    {                                  // siH: 256 h2 (bias pre-folded)
        const int rr = t >> 4, k2 = t & 15;
        const float2 v = *(const float2*)&ws_si[(size_t)b * 2048 + (size_t)(qi * 16 + rr) * 32 + 2 * k2];
        h2 p; p[0] = (_Float16)v.x; p[1] = (_Float16)v.y;
        siH[rr * SJH + k2] = p;
    }
    if (t < 32)      bE2s[t] = bE2[t];
    else if (t < 64) E3s[t - 32] = E3[t - 32];

    // ---- A-frags: E2^T in f16 (mapping HW-validated rounds 4-9) ----
    h8 aE00, aE10, aE01, aE11;
#pragma unroll
    for (int e = 0; e < 8; ++e) {
        aE00[e] = (_Float16)E2[(size_t)(8 * g + e) * 32 + r];
        aE10[e] = (_Float16)E2[(size_t)(8 * g + e + 32) * 32 + r];
        aE01[e] = (_Float16)E2[(size_t)(8 * g + e) * 32 + r + 16];
        aE11[e] = (_Float16)E2[(size_t)(8 * g + e + 32) * 32 + r + 16];
    }
    const float bE3v = bE3[0], bS2v = bS2[0];
    const h4 z4 = {(_Float16)0.f, (_Float16)0.f, (_Float16)0.f, (_Float16)0.f};
    __syncthreads();

    // ---- hoist ei fragments (jt-invariant; 16 h4 = 32 VGPR) ----
    h4 ei0a[4], ei0b[4], ei1a[4], ei1b[4];
#pragma unroll
    for (int ii = 0; ii < 4; ++ii) {
        const int il = 4 * w + ii;
        ei0a[ii] = *(const h4*)&eiH[il * EJH + 4 * g];
        ei0b[ii] = *(const h4*)&eiH[il * EJH + 4 * g + 2];
        ei1a[ii] = *(const h4*)&eiH[il * EJH + 16 + 4 * g];
        ei1b[ii] = *(const h4*)&eiH[il * EJH + 16 + 4 * g + 2];
    }

    // ---- E pass: wave w owns i-rows 4w..4w+3; j-tiles 0..3 ----
    for (int jt = 0; jt < 4; ++jt) {
        const int j = (jt << 4) + r;
        const h4 ej0a = *(const h4*)&ejH[j * EJH + 4 * g];
        const h4 ej0b = *(const h4*)&ejH[j * EJH + 4 * g + 2];
        const h4 ej1a = *(const h4*)&ejH[j * EJH + 16 + 4 * g];
        const h4 ej1b = *(const h4*)&ejH[j * EJH + 16 + 4 * g + 2];

#pragma unroll
        for (int ii = 0; ii < 4; ++ii) {
            const int ig = qi * 16 + 4 * w + ii;

            const h4 he0a = __builtin_elementwise_max(ei0a[ii] + ej0a, z4);
            const h4 he0b = __builtin_elementwise_max(ei0b[ii] + ej0b, z4);
            const h4 he1a = __builtin_elementwise_max(ei1a[ii] + ej1a, z4);
            const h4 he1b = __builtin_elementwise_max(ei1b[ii] + ej1b, z4);
            const h8 b0 = __builtin_shufflevector(he0a, he0b, 0, 1, 2, 3, 4, 5, 6, 7);
            const h8 b1 = __builtin_shufflevector(he1a, he1b, 0, 1, 2, 3, 4, 5, 6, 7);

            f32x4 acc0 = {0.f, 0.f, 0.f, 0.f};
            f32x4 acc1 = {0.f, 0.f, 0.f, 0.f};
            acc0 = __builtin_amdgcn_mfma_f32_16x16x32_f16(aE00, b0, acc0, 0, 0, 0);
            acc0 = __builtin_amdgcn_mfma_f32_16x16x32_f16(aE10, b1, acc0, 0, 0, 0);
            acc1 = __builtin_amdgcn_mfma_f32_16x16x32_f16(aE01, b0, acc1, 0, 0, 0);
            acc1 = __builtin_amdgcn_mfma_f32_16x16x32_f16(aE11, b1, acc1, 0, 0, 0);

            float pe = 0.f;
#pragma unroll
            for (int q = 0; q < 4; ++q) {
                const int k0 = 4 * g + q;
                pe += fmaxf(acc0[q] + bE2s[k0], 0.f) * E3s[k0];
                pe += fmaxf(acc1[q] + bE2s[k0 + 16], 0.f) * E3s[k0 + 16];
            }
            pe += __shfl_xor(pe, 16);
            pe += __shfl_xor(pe, 32);

            if (l < 16) {
                const float z = pe + bE3v;
                const float p = 1.0f / (1.0f + __expf(-z));
                const float av = (j == ig || !(p > 0.3f)) ? 0.f : p;
                out_adj[(size_t)b * 4096 + (size_t)ig * 64 + j] = av;
            }
        }
    }

    // ---- S pass: packed f16 + fdot2 (S2/sj loads deferred to here) ----
    {
        h4 s2h[8];
#pragma unroll
        for (int q8 = 0; q8 < 8; ++q8) {
            h4 p;
            p[0] = (_Float16)S2[4 * q8];     p[1] = (_Float16)S2[4 * q8 + 1];
            p[2] = (_Float16)S2[4 * q8 + 2]; p[3] = (_Float16)S2[4 * q8 + 3];
            s2h[q8] = p;
        }
        const int j = t & 63;
        const int ib = (t >> 6) * 4;
        h4 sj4[8];
#pragma unroll
        for (int q8 = 0; q8 < 8; ++q8)
            sj4[q8] = *(const h4*)&sjH[j * SJH + 2 * q8];
#pragma unroll
        for (int ii = 0; ii < 4; ++ii) {
            const int il = ib + ii;
            const int ig = qi * 16 + il;
            float sacc = 0.f;
#pragma unroll
            for (int q8 = 0; q8 < 8; ++q8) {
                const h4 si4 = *(const h4*)&siH[il * SJH + 2 * q8];   // broadcast
                const h4 hs = __builtin_elementwise_max(si4 + sj4[q8], z4);
                const h2 lo   = __builtin_shufflevector(hs, hs, 0, 1);
                const h2 hi   = __builtin_shufflevector(hs, hs, 2, 3);
                const h2 s2lo = __builtin_shufflevector(s2h[q8], s2h[q8], 0, 1);
                const h2 s2hi = __builtin_shufflevector(s2h[q8], s2h[q8], 2, 3);
                sacc = __builtin_amdgcn_fdot2(lo, s2lo, sacc, false);
                sacc = __builtin_amdgcn_fdot2(hi, s2hi, sacc, false);
            }
            const float xs = sacc + bS2v;
            const float e2x = __expf(2.0f * xs);
            const float sv = (j == ig) ? 0.f : (e2x - 1.0f) / (e2x + 1.0f);
            out_str[(size_t)b * 4096 + (size_t)ig * 64 + j] = sv;
        }
    }
}

extern "C" void kernel_launch(void* const* d_in, const int* in_sizes, int n_in,
                              void* d_out, int out_size, void* d_ws, size_t ws_size,
                              hipStream_t stream)
{
    const float* x     = (const float*)d_in[0];
    const float* W1    = (const float*)d_in[1];
    const float* b1    = (const float*)d_in[2];
    const float* W2    = (const float*)d_in[3];
    const float* b2    = (const float*)d_in[4];
    const float* gamma = (const float*)d_in[5];
    const float* beta  = (const float*)d_in[6];
    const float* E1    = (const float*)d_in[7];
    const float* bE1   = (const float*)d_in[8];
    const float* E2    = (const float*)d_in[9];
    const float* bE2   = (const float*)d_in[10];
    const float* E3    = (const float*)d_in[11];
    const float* bE3   = (const float*)d_in[12];
    const float* S1    = (const float*)d_in[13];
    const float* bS1   = (const float*)d_in[14];
    const float* S2    = (const float*)d_in[15];
    const float* bS2   = (const float*)d_in[16];

    float* out     = (float*)d_out;
    float* out_nf  = out;                // 256*64*64
    float* out_adj = out + 1048576;
    float* out_str = out + 2097152;

    // d_ws layout: wT (104 KB, shorts) | ei 4MB | ej 4MB | si 2MB | sj 2MB
    short* wT    = (short*)d_ws;
    float* wsf   = (float*)d_ws;
    float* ws_ei = wsf + 32768;          // 128 KB offset
    float* ws_ej = ws_ei + 1048576;
    float* ws_si = ws_ej + 1048576;
    float* ws_sj = ws_si + 524288;

    kernelA0<<<128, 256, 0, stream>>>(W1, W2, E1, S1, wT);

    kernelN<<<dim3(4, 256), 256, 0, stream>>>(
        x, b1, b2, gamma, beta, wT, bE1, bS1,
        out_nf, ws_ei, ws_ej, ws_si, ws_sj);

    kernelB<<<dim3(4, 256), 256, 0, stream>>>(
        ws_ei, ws_ej, ws_si, ws_sj,
        E2, bE2, E3, bE3, S2, bS2,
        out_adj, out_str);
}

// Round 11
// 39.022 us; speedup vs baseline: 1.4568x; 1.1738x over previous
//
#include <hip/hip_runtime.h>
#include <hip/hip_bf16.h>
#include <math.h>

typedef __attribute__((ext_vector_type(8))) short short8;
typedef __attribute__((ext_vector_type(4))) short short4v;
typedef __attribute__((ext_vector_type(4))) float f32x4;
typedef __attribute__((ext_vector_type(2))) _Float16 h2;
typedef __attribute__((ext_vector_type(4))) _Float16 h4;
typedef __attribute__((ext_vector_type(8))) _Float16 h8;

__device__ __forceinline__ short f2bf(float f) {
    __hip_bfloat16 h = __float2bfloat16(f);   // RNE; pairs fuse to v_cvt_pk_bf16_f32
    return __builtin_bit_cast(short, h);
}

// ============================================================================
// Kernel A0 (unchanged from round 10): weight transpose + bf16 into d_ws.
// wT layout (shorts): W1T [128n][256k] @0 | W2T [64n][128k] @32768 |
//                     WcatT [192o][64k] @40960  (Wcat = [E1a|E1b|S1a|S1b])
// ============================================================================
__global__ __launch_bounds__(256)
void kernelA0(const float* __restrict__ W1, const float* __restrict__ W2,
              const float* __restrict__ E1, const float* __restrict__ S1,
              short* __restrict__ wT)
{
    const int tid = blockIdx.x * 256 + threadIdx.x;   // 32768
    {   // W1 [256k][128n] -> W1T[n][k]
        const int k = tid >> 7, n = tid & 127;
        wT[n * 256 + k] = f2bf(W1[tid]);
    }
    if (tid < 8192) {   // W2 [128k][64n] -> W2T[n][k]
        const int k = tid >> 6, n = tid & 63;
        wT[32768 + n * 128 + k] = f2bf(W2[tid]);
    }
    if (tid < 8192) {   // E1 [128][64] -> WcatT cols 0..127
        const int rr = tid >> 6, c = tid & 63;
        const int o = (rr < 64) ? c : (64 + c);
        const int k = (rr < 64) ? rr : (rr - 64);
        wT[40960 + o * 64 + k] = f2bf(E1[tid]);
    }
    if (tid < 4096) {   // S1 [128][32] -> WcatT cols 128..191
        const int rr = tid >> 5, c = tid & 31;
        const int o = (rr < 64) ? (128 + c) : (160 + c);
        const int k = (rr < 64) ? rr : (rr - 64);
        wT[40960 + o * 64 + k] = f2bf(S1[tid]);
    }
}

// ============================================================================
// Kernel F (round 11): FULLY FUSED per-batch pipeline, 1024 threads (16 waves)
// per block, grid 256 -> 1 block/CU, 4 waves/SIMD (round 10's TLP, which the
// round-7 4-wave fusion lacked) with ZERO ws round-trip and ONE launch.
// Dynamic LDS 68.4 KB with region aliasing:
//   [0,33280)   Xs (bf16 X rows)      -> after ph2: eiH/ejH/siH/sjH (f16)
//   [33280,..)  h1B (bf16)            -> after ph3: nfB (bf16)
//   [50688,..)  Hs (f32)
// MFMA mapping HW-validated rounds 4-10: A[row=l&15][k=8*(l>>4)+e],
// B[k=8*(l>>4)+e][col=l&15], D[row=4*(l>>4)+q][col=l&15].
// ============================================================================
constexpr int XS_S  = 260;  // shorts/row (130 dw, %32=2 -> 2-way free)
constexpr int H1B_S = 136;  // shorts (68 dw, %32=4 -> 2-way free)
constexpr int HS_S  = 68;   // floats (%32=4)
constexpr int NNF_S = 72;   // shorts (36 dw, %32=4)
constexpr int EJW   = 68;   // halfs/row for ei/ej (34 dw, %32=2)
constexpr int SJW   = 36;   // halfs/row for si/sj (18 dw stride in dw terms: 9 dw? 36 halfs=18 dw, %32=18)

constexpr int OFF_XS  = 0;          // 33280 B
constexpr int OFF_EIH = 0;          // 8704 B  (64*68*2)
constexpr int OFF_EJH = 8704;       // 8704 B
constexpr int OFF_SIH = 17408;      // 4608 B  (64*36*2)
constexpr int OFF_SJH = 22016;      // 4608 B  -> ends 26624 <= 33280
constexpr int OFF_H1B = 33280;      // 17408 B ; nfB alias
constexpr int OFF_HS  = 50688;      // 17408 B
constexpr int LDS_BYTES = 68096;

__global__ __launch_bounds__(1024)
void kernelF(const float* __restrict__ x,
             const float* __restrict__ b1, const float* __restrict__ b2,
             const float* __restrict__ gamma, const float* __restrict__ beta,
             const short* __restrict__ wT,
             const float* __restrict__ bE1, const float* __restrict__ E2,
             const float* __restrict__ bE2, const float* __restrict__ E3,
             const float* __restrict__ bE3, const float* __restrict__ bS1,
             const float* __restrict__ S2, const float* __restrict__ bS2,
             float* __restrict__ out_nf, float* __restrict__ out_adj,
             float* __restrict__ out_str)
{
    extern __shared__ char lds[];
    short*    XsS  = (short*)(lds + OFF_XS);
    short*    h1BS = (short*)(lds + OFF_H1B);
    float*    HsS  = (float*)(lds + OFF_HS);
    short*    nfBS = (short*)(lds + OFF_H1B);   // alias (h1B dead after ph3)
    _Float16* eihS = (_Float16*)(lds + OFF_EIH);// alias (Xs dead after ph2)
    _Float16* ejhS = (_Float16*)(lds + OFF_EJH);
    _Float16* sihS = (_Float16*)(lds + OFF_SIH);
    _Float16* sjhS = (_Float16*)(lds + OFF_SJH);
    __shared__ float bE2s[32], E3s[32];

    const int t = threadIdx.x, b = blockIdx.x;
    const int w = t >> 6, l = t & 63, g = l >> 4, r = l & 15;
    const short* W1T = wT;
    const short* W2T = wT + 32768;
    const short* WcT = wT + 40960;

    if (t < 32)      bE2s[t] = bE2[t];
    else if (t < 64) E3s[t - 32] = E3[t - 32];

    // ---- A-frags for edge MFMA: E2^T in f16 (global, L2-hit) ----
    h8 aE00, aE10, aE01, aE11;
#pragma unroll
    for (int e = 0; e < 8; ++e) {
        aE00[e] = (_Float16)E2[(size_t)(8 * g + e) * 32 + r];
        aE10[e] = (_Float16)E2[(size_t)(8 * g + e + 32) * 32 + r];
        aE01[e] = (_Float16)E2[(size_t)(8 * g + e) * 32 + r + 16];
        aE11[e] = (_Float16)E2[(size_t)(8 * g + e + 32) * 32 + r + 16];
    }
    const float bE3v = bE3[0], bS2v = bS2[0];
    const h4 z4 = {(_Float16)0.f, (_Float16)0.f, (_Float16)0.f, (_Float16)0.f};

    // ---- stage X coalesced (64 rows, 16 threads/row, cvt bf16) ----
    {
        const int row = t >> 4, c0 = t & 15;
        const int srow = (row == 63) ? 127 : (int)((float)row * (127.0f / 63.0f));
        const float* xrow = x + ((size_t)b * 128 + srow) * 256;
#pragma unroll
        for (int i = 0; i < 4; ++i) {
            const int c4 = (c0 + 16 * i) * 4;
            const float4 v = *(const float4*)(xrow + c4);
            short4v s;
            s[0] = f2bf(v.x); s[1] = f2bf(v.y); s[2] = f2bf(v.z); s[3] = f2bf(v.w);
            *(short4v*)&XsS[row * XS_S + c4] = s;
        }
    }
    __syncthreads();

    // ---- ph2: h1[64][128] = relu(X@W1+b1); wave w: M-tile w>>2, N-tiles (w&3)*2+{0,1} ----
    {
        const int mt = w >> 2, nb = (w & 3) << 1;
        const int aRow = (16 * mt + r) * XS_S;
#pragma unroll
        for (int np = 0; np < 2; ++np) {
            const int n = ((nb + np) << 4) + r;
            f32x4 acca = {0.f, 0.f, 0.f, 0.f};
            f32x4 accb = {0.f, 0.f, 0.f, 0.f};
#pragma unroll
            for (int ks = 0; ks < 4; ++ks) {
                const short8 a0  = *(const short8*)&XsS[aRow + 32 * ks + 8 * g];
                const short8 a1  = *(const short8*)&XsS[aRow + 32 * (ks + 4) + 8 * g];
                const short8 bwa = *(const short8*)(W1T + (size_t)n * 256 + 32 * ks + 8 * g);
                const short8 bwb = *(const short8*)(W1T + (size_t)n * 256 + 32 * (ks + 4) + 8 * g);
                acca = __builtin_amdgcn_mfma_f32_16x16x32_bf16(a0, bwa, acca, 0, 0, 0);
                accb = __builtin_amdgcn_mfma_f32_16x16x32_bf16(a1, bwb, accb, 0, 0, 0);
            }
            const float b1v = b1[n];
#pragma unroll
            for (int q = 0; q < 4; ++q)
                h1BS[(16 * mt + 4 * g + q) * H1B_S + n] = f2bf(fmaxf(acca[q] + accb[q] + b1v, 0.f));
        }
    }
    __syncthreads();

    // ---- ph3: h[64][64] = h1@W2+b2; wave w: tile (w>>2, w&3) ----
    {
        const int mt = w >> 2;
        const int n = ((w & 3) << 4) + r;
        const int aRow = (16 * mt + r) * H1B_S;
        f32x4 acca = {0.f, 0.f, 0.f, 0.f};
        f32x4 accb = {0.f, 0.f, 0.f, 0.f};
#pragma unroll
        for (int ks2 = 0; ks2 < 2; ++ks2) {
            const short8 ha0 = *(const short8*)&h1BS[aRow + 32 * (2 * ks2) + 8 * g];
            const short8 ha1 = *(const short8*)&h1BS[aRow + 32 * (2 * ks2 + 1) + 8 * g];
            const short8 bw0 = *(const short8*)(W2T + (size_t)n * 128 + 32 * (2 * ks2) + 8 * g);
            const short8 bw1 = *(const short8*)(W2T + (size_t)n * 128 + 32 * (2 * ks2 + 1) + 8 * g);
            acca = __builtin_amdgcn_mfma_f32_16x16x32_bf16(ha0, bw0, acca, 0, 0, 0);
            accb = __builtin_amdgcn_mfma_f32_16x16x32_bf16(ha1, bw1, accb, 0, 0, 0);
        }
        const float b2v = b2[n];
#pragma unroll
        for (int q = 0; q < 4; ++q)
            HsS[(16 * mt + 4 * g + q) * HS_S + n] = acca[q] + accb[q] + b2v;
    }
    __syncthreads();

    // ---- ph4: LayerNorm; row = t>>4 (64 rows x 16 lanes exactly) ----
    {
        const int row = t >> 4, c4 = (t & 15) * 4;
        const float4 v = *(const float4*)&HsS[row * HS_S + c4];
        float s = v.x + v.y + v.z + v.w;
        s += __shfl_xor(s, 1); s += __shfl_xor(s, 2);
        s += __shfl_xor(s, 4); s += __shfl_xor(s, 8);
        const float mu = s * (1.0f / 64.0f);
        float vs = 0.f;
        { const float d0 = v.x-mu, d1 = v.y-mu, d2 = v.z-mu, d3 = v.w-mu;
          vs = fmaf(d0,d0, fmaf(d1,d1, fmaf(d2,d2, d3*d3))); }
        vs += __shfl_xor(vs, 1); vs += __shfl_xor(vs, 2);
        vs += __shfl_xor(vs, 4); vs += __shfl_xor(vs, 8);
        const float rstd = rsqrtf(vs * (1.0f / 64.0f) + 1e-5f);
        const float4 gv = *(const float4*)(gamma + c4);
        const float4 bv = *(const float4*)(beta  + c4);
        float4 o;
        o.x = fmaf((v.x - mu) * rstd, gv.x, bv.x);
        o.y = fmaf((v.y - mu) * rstd, gv.y, bv.y);
        o.z = fmaf((v.z - mu) * rstd, gv.z, bv.z);
        o.w = fmaf((v.w - mu) * rstd, gv.w, bv.w);
        *(float4*)(out_nf + (size_t)b * 4096 + (size_t)row * 64 + c4) = o;
        short4v ob;
        ob[0] = f2bf(o.x); ob[1] = f2bf(o.y); ob[2] = f2bf(o.z); ob[3] = f2bf(o.w);
        *(short4v*)&nfBS[row * NNF_S + c4] = ob;   // overwrites dead h1B region
    }
    __syncthreads();

    // ---- ph5: [ei|ej|si|sj] = nf@Wcat -> f16 LDS (Xs region), biases folded ----
    {
        const int mt = w >> 2;
        const short8 na0 = *(const short8*)&nfBS[(16 * mt + r) * NNF_S + 8 * g];
        const short8 na1 = *(const short8*)&nfBS[(16 * mt + r) * NNF_S + 32 + 8 * g];
#pragma unroll
        for (int k3 = 0; k3 < 3; ++k3) {
            const int ot = (w & 3) * 3 + k3;         // 0..11
            const int c = 16 * ot + r;
            const short8 bw0 = *(const short8*)(WcT + (size_t)c * 64 + 8 * g);
            const short8 bw1 = *(const short8*)(WcT + (size_t)c * 64 + 32 + 8 * g);
            f32x4 acc = {0.f, 0.f, 0.f, 0.f};
            acc = __builtin_amdgcn_mfma_f32_16x16x32_bf16(na0, bw0, acc, 0, 0, 0);
            acc = __builtin_amdgcn_mfma_f32_16x16x32_bf16(na1, bw1, acc, 0, 0, 0);
            if (ot < 4) {
                const float bv = bE1[c];
#pragma unroll
                for (int q = 0; q < 4; ++q)
                    eihS[(16 * mt + 4 * g + q) * EJW + c] = (_Float16)(acc[q] + bv);
            } else if (ot < 8) {
#pragma unroll
                for (int q = 0; q < 4; ++q)
                    ejhS[(16 * mt + 4 * g + q) * EJW + (c - 64)] = (_Float16)acc[q];
            } else if (ot < 10) {
                const float bv = bS1[c - 128];
#pragma unroll
                for (int q = 0; q < 4; ++q)
                    sihS[(16 * mt + 4 * g + q) * SJW + (c - 128)] = (_Float16)(acc[q] + bv);
            } else {
#pragma unroll
                for (int q = 0; q < 4; ++q)
                    sjhS[(16 * mt + 4 * g + q) * SJW + (c - 160)] = (_Float16)acc[q];
            }
        }
    }
    __syncthreads();

    // ---- E pass: wave w owns i-rows 4w..4w+3; j-tiles 0..3 ----
    {
        // hoist jt-invariant ei fragments (4 rows x 4 h4 = 32 VGPR)
        h4 ei0a[4], ei0b[4], ei1a[4], ei1b[4];
#pragma unroll
        for (int ii = 0; ii < 4; ++ii) {
            const int il = 4 * w + ii;
            ei0a[ii] = *(const h4*)&eihS[il * EJW + 8 * g];
            ei0b[ii] = *(const h4*)&eihS[il * EJW + 8 * g + 4];
            ei1a[ii] = *(const h4*)&eihS[il * EJW + 32 + 8 * g];
            ei1b[ii] = *(const h4*)&eihS[il * EJW + 32 + 8 * g + 4];
        }

        for (int jt = 0; jt < 4; ++jt) {
            const int j = (jt << 4) + r;
            const h4 ej0a = *(const h4*)&ejhS[j * EJW + 8 * g];
            const h4 ej0b = *(const h4*)&ejhS[j * EJW + 8 * g + 4];
            const h4 ej1a = *(const h4*)&ejhS[j * EJW + 32 + 8 * g];
            const h4 ej1b = *(const h4*)&ejhS[j * EJW + 32 + 8 * g + 4];

#pragma unroll
            for (int ii = 0; ii < 4; ++ii) {
                const int ig = 4 * w + ii;

                const h4 he0a = __builtin_elementwise_max(ei0a[ii] + ej0a, z4);
                const h4 he0b = __builtin_elementwise_max(ei0b[ii] + ej0b, z4);
                const h4 he1a = __builtin_elementwise_max(ei1a[ii] + ej1a, z4);
                const h4 he1b = __builtin_elementwise_max(ei1b[ii] + ej1b, z4);
                const h8 b0 = __builtin_shufflevector(he0a, he0b, 0, 1, 2, 3, 4, 5, 6, 7);
                const h8 b1 = __builtin_shufflevector(he1a, he1b, 0, 1, 2, 3, 4, 5, 6, 7);

                f32x4 acc0 = {0.f, 0.f, 0.f, 0.f};
                f32x4 acc1 = {0.f, 0.f, 0.f, 0.f};
                acc0 = __builtin_amdgcn_mfma_f32_16x16x32_f16(aE00, b0, acc0, 0, 0, 0);
                acc0 = __builtin_amdgcn_mfma_f32_16x16x32_f16(aE10, b1, acc0, 0, 0, 0);
                acc1 = __builtin_amdgcn_mfma_f32_16x16x32_f16(aE01, b0, acc1, 0, 0, 0);
                acc1 = __builtin_amdgcn_mfma_f32_16x16x32_f16(aE11, b1, acc1, 0, 0, 0);

                float pe = 0.f;
#pragma unroll
                for (int q = 0; q < 4; ++q) {
                    const int k0 = 4 * g + q;
                    pe += fmaxf(acc0[q] + bE2s[k0], 0.f) * E3s[k0];
                    pe += fmaxf(acc1[q] + bE2s[k0 + 16], 0.f) * E3s[k0 + 16];
                }
                pe += __shfl_xor(pe, 16);
                pe += __shfl_xor(pe, 32);

                if (l < 16) {
                    const float z = pe + bE3v;
                    const float p = 1.0f / (1.0f + __expf(-z));
                    const float av = (j == ig || !(p > 0.3f)) ? 0.f : p;
                    out_adj[(size_t)b * 4096 + (size_t)ig * 64 + j] = av;
                }
            }
        }
    }

    // ---- S pass: thread t: j = t&63, i-rows (t>>6)*4.. ; fdot2 ----
    {
        h4 s2h[8];
#pragma unroll
        for (int q8 = 0; q8 < 8; ++q8) {
            h4 p;
            p[0] = (_Float16)S2[4 * q8];     p[1] = (_Float16)S2[4 * q8 + 1];
            p[2] = (_Float16)S2[4 * q8 + 2]; p[3] = (_Float16)S2[4 * q8 + 3];
            s2h[q8] = p;
        }
        const int j = t & 63;
        const int ib = (t >> 6) * 4;
        h4 sj4[8];
#pragma unroll
        for (int q8 = 0; q8 < 8; ++q8)
            sj4[q8] = *(const h4*)&sjhS[j * SJW + 4 * q8];
#pragma unroll
        for (int ii = 0; ii < 4; ++ii) {
            const int ig = ib + ii;
            float sacc = 0.f;
#pragma unroll
            for (int q8 = 0; q8 < 8; ++q8) {
                const h4 si4 = *(const h4*)&sihS[ig * SJW + 4 * q8];   // broadcast
                const h4 hs = __builtin_elementwise_max(si4 + sj4[q8], z4);
                const h2 lo   = __builtin_shufflevector(hs, hs, 0, 1);
                const h2 hi   = __builtin_shufflevector(hs, hs, 2, 3);
                const h2 s2lo = __builtin_shufflevector(s2h[q8], s2h[q8], 0, 1);
                const h2 s2hi = __builtin_shufflevector(s2h[q8], s2h[q8], 2, 3);
                sacc = __builtin_amdgcn_fdot2(lo, s2lo, sacc, false);
                sacc = __builtin_amdgcn_fdot2(hi, s2hi, sacc, false);
            }
            const float xs = sacc + bS2v;
            const float e2x = __expf(2.0f * xs);
            const float sv = (j == ig) ? 0.f : (e2x - 1.0f) / (e2x + 1.0f);
            out_str[(size_t)b * 4096 + (size_t)ig * 64 + j] = sv;
        }
    }
}

extern "C" void kernel_launch(void* const* d_in, const int* in_sizes, int n_in,
                              void* d_out, int out_size, void* d_ws, size_t ws_size,
                              hipStream_t stream)
{
    const float* x     = (const float*)d_in[0];
    const float* W1    = (const float*)d_in[1];
    const float* b1    = (const float*)d_in[2];
    const float* W2    = (const float*)d_in[3];
    const float* b2    = (const float*)d_in[4];
    const float* gamma = (const float*)d_in[5];
    const float* beta  = (const float*)d_in[6];
    const float* E1    = (const float*)d_in[7];
    const float* bE1   = (const float*)d_in[8];
    const float* E2    = (const float*)d_in[9];
    const float* bE2   = (const float*)d_in[10];
    const float* E3    = (const float*)d_in[11];
    const float* bE3   = (const float*)d_in[12];
    const float* S1    = (const float*)d_in[13];
    const float* bS1   = (const float*)d_in[14];
    const float* S2    = (const float*)d_in[15];
    const float* bS2   = (const float*)d_in[16];

    float* out     = (float*)d_out;
    float* out_nf  = out;                // 256*64*64
    float* out_adj = out + 1048576;
    float* out_str = out + 2097152;

    short* wT = (short*)d_ws;            // 104 KB scratch, rewritten every call

    (void)hipFuncSetAttribute((const void*)kernelF,
        hipFuncAttributeMaxDynamicSharedMemorySize, LDS_BYTES);

    kernelA0<<<128, 256, 0, stream>>>(W1, W2, E1, S1, wT);

    kernelF<<<256, 1024, LDS_BYTES, stream>>>(
        x, b1, b2, gamma, beta, wT,
        bE1, E2, bE2, E3, bE3, bS1, S2, bS2,
        out_nf, out_adj, out_str);
}